// Round 15
// baseline (562.390 us; speedup 1.0000x reference)
//
#include <hip/hip_runtime.h>
#include <hip/hip_bf16.h>

#define NN 50000
#define EE 1600000
#define DIM 256
#define KDIM 512
#define NLAYER 3
#define NRANGE 8
#define RNODES (NN / NRANGE)   // 6250
#define CAP 80                 // fixed CSR row capacity (multiple of 16); P(deg>80) ~ 1e-17

using bf16x8 = __attribute__((ext_vector_type(8))) short;
using f32x4  = __attribute__((ext_vector_type(4))) float;
using f32x2  = __attribute__((ext_vector_type(2))) float;

static __device__ __forceinline__ unsigned short f2bf(float f) {
    unsigned u = __builtin_bit_cast(unsigned, f);
    unsigned r = (u + 0x7FFFu + ((u >> 16) & 1u)) >> 16;   // RNE
    return (unsigned short)r;
}
static __device__ __forceinline__ float bf2f(unsigned short s) {
    return __builtin_bit_cast(float, (unsigned)s << 16);
}

// ---- async global->LDS, 16B per lane. LDS dest is wave-uniform base + lane*16 (G21).
static __device__ __forceinline__ void gload_lds16(const void* g, void* l) {
    __builtin_amdgcn_global_load_lds(
        reinterpret_cast<const __attribute__((address_space(1))) void*>(
            reinterpret_cast<uintptr_t>(g)),
        reinterpret_cast<__attribute__((address_space(3))) void*>(
            static_cast<unsigned>(reinterpret_cast<uintptr_t>(l))),
        16, 0, 0);
}

// ---- fp8 e4m3 (OCP) helpers ----
#if defined(__has_builtin) && __has_builtin(__builtin_amdgcn_cvt_pk_f32_fp8) && __has_builtin(__builtin_amdgcn_cvt_pk_fp8_f32)
#define FP8_NATIVE 1
#else
#define FP8_NATIVE 0
#endif

template <bool HI>
static __device__ __forceinline__ f32x2 fp8x2_dec(unsigned w) {
#if FP8_NATIVE
    return __builtin_amdgcn_cvt_pk_f32_fp8((int)w, HI);
#else
    unsigned v = HI ? (w >> 16) : w;
    unsigned b0 = v & 0xFFu, b1 = (v >> 8) & 0xFFu;
    unsigned u0 = ((b0 & 0x80u) << 24) | ((b0 & 0x7Fu) << 20);
    unsigned u1 = ((b1 & 0x80u) << 24) | ((b1 & 0x7Fu) << 20);
    f32x2 r;
    r[0] = __builtin_bit_cast(float, u0) * 0x1p120f;
    r[1] = __builtin_bit_cast(float, u1) * 0x1p120f;
    return r;
#endif
}

#if !FP8_NATIVE
static __device__ __forceinline__ unsigned fp8_enc1(float f) {
    unsigned u = __builtin_bit_cast(unsigned, f * 0x1p-120f);
    unsigned s = (u >> 24) & 0x80u;
    unsigned m = u & 0x7FFFFFFFu;
    m = m + 0x7FFFFu + ((m >> 20) & 1u);
    return s | ((m >> 20) & 0x7Fu);
}
#endif

static __device__ __forceinline__ unsigned fp8x4_enc(float a, float b, float c, float d) {
#if FP8_NATIVE
    int w = __builtin_amdgcn_cvt_pk_fp8_f32(a, b, 0, false);
    w = __builtin_amdgcn_cvt_pk_fp8_f32(c, d, w, true);
    return (unsigned)w;
#else
    return fp8_enc1(a) | (fp8_enc1(b) << 8) | (fp8_enc1(c) << 16) | (fp8_enc1(d) << 24);
#endif
}

static __device__ __forceinline__ void fp8x8_fma(float* acc, unsigned lo, unsigned hi, float wg) {
    f32x2 p0 = fp8x2_dec<false>(lo);
    f32x2 p1 = fp8x2_dec<true>(lo);
    f32x2 p2 = fp8x2_dec<false>(hi);
    f32x2 p3 = fp8x2_dec<true>(hi);
    acc[0] += wg * p0[0]; acc[1] += wg * p0[1];
    acc[2] += wg * p1[0]; acc[3] += wg * p1[1];
    acc[4] += wg * p2[0]; acc[5] += wg * p2[1];
    acc[6] += wg * p3[0]; acc[7] += wg * p3[1];
}

static __device__ __forceinline__ void fp8x16_fma(float* acc, uint4 r, float wg) {
    fp8x8_fma(acc, r.x, r.y, wg);
    fp8x8_fma(acc + 8, r.z, r.w, wg);
}

// ---------------- prep: x (fp32) -> h0 (bf16 + fp8), e_src0 = exp(x . w_src0) ----------------
__global__ __launch_bounds__(256) void k_prep(const float* __restrict__ x,
                                              const float* __restrict__ w_src,
                                              unsigned short* __restrict__ hout,
                                              unsigned char* __restrict__ f8out,
                                              float* __restrict__ e_src) {
    int wave = threadIdx.x >> 6, lane = threadIdx.x & 63;
    int n = blockIdx.x * 4 + wave;
    if (n >= NN) return;
    const float4 v = *reinterpret_cast<const float4*>(x + (size_t)n * DIM + lane * 4);
    const float4 wv = *reinterpret_cast<const float4*>(w_src + lane * 4);
    float sc = v.x * wv.x + v.y * wv.y + v.z * wv.z + v.w * wv.w;
    #pragma unroll
    for (int m = 32; m; m >>= 1) sc += __shfl_xor(sc, m);
    if (lane == 0) e_src[n] = __expf(sc);
    ushort4 o;
    o.x = f2bf(v.x); o.y = f2bf(v.y); o.z = f2bf(v.z); o.w = f2bf(v.w);
    *reinterpret_cast<ushort4*>(hout + (size_t)n * DIM + lane * 4) = o;
    *reinterpret_cast<unsigned*>(f8out + (size_t)n * DIM + lane * 4) =
        fp8x4_enc(v.x, v.y, v.z, v.w);
}

// ---------------- CSR build: single range-partitioned scatter into fixed-CAP rows ----------
__global__ __launch_bounds__(256) void k_scatter(const int* __restrict__ ei, int* __restrict__ cursor,
                                                 unsigned short* __restrict__ csr) {
    const int range = blockIdx.x & (NRANGE - 1);
    const int lo = range * RNODES, hi = lo + RNODES;
    const int stride = (gridDim.x >> 3) * 256;
    for (int e = (blockIdx.x >> 3) * 256 + threadIdx.x; e < EE; e += stride) {
        int d = ei[EE + e];
        if (d >= lo && d < hi) {
            int pos = atomicAdd(&cursor[d], 1);
            if (pos < CAP) csr[d * CAP + pos] = (unsigned short)ei[e];
        }
    }
}

// ---------------- pad rows to multiple of 16 with sentinel edges (index NN: zero row) ------
__global__ __launch_bounds__(256) void k_pad(int* __restrict__ cursor,
                                             unsigned short* __restrict__ csr) {
    int n = blockIdx.x * 256 + threadIdx.x;
    if (n >= NN) return;
    int deg = cursor[n];
    if (deg > CAP) deg = CAP;
    int padded = (deg + 15) & ~15;
    if (padded > CAP) padded = CAP;
    for (int p = deg; p < padded; ++p) csr[(size_t)n * CAP + p] = (unsigned short)NN;
    cursor[n] = padded;
}

// ---------------- pack W (fp32 [512][256]) -> Bp bf16, lane-linear MFMA-B fragments ---------
__global__ __launch_bounds__(256) void k_packB(const float* __restrict__ W, unsigned short* __restrict__ Bp) {
    int tid = blockIdx.x * 256 + threadIdx.x;
    int j    = tid & 7;
    int lane = (tid >> 3) & 63;
    int nf   = (tid >> 9) & 15;
    int ks   = tid >> 13;
    int c = lane & 15, q = lane >> 4;
    Bp[tid] = f2bf(W[(size_t)(ks * 32 + q * 8 + j) * DIM + nf * 16 + c]);
}

// ---------------- FUSED: aggregate(16 nodes/wave) + MFMA GEMM + LN + ReLU + packs ----------
// Phase 1: wave aggregates exactly the 16 rows it consumes as GEMM A-rows (quarter-wave
// gather), writes them to block-private global agg rows; s_waitcnt vmcnt(0) orders RAW.
// Phase 2: unchanged LDS-staged MFMA GEMM reading hin (ks<8) and agg (ks>=8).
// Blocks in phase 1 (gather-latency) co-schedule with blocks in phase 2 (MFMA) per CU.
#define LDS_STRIDE 264
__global__ __launch_bounds__(256) void k_agg_gemm(const unsigned char* __restrict__ f8,
                                                  const float* __restrict__ e_in,
                                                  const int* __restrict__ cursor,
                                                  const unsigned short* __restrict__ csr,
                                                  unsigned short* __restrict__ aggbuf,
                                                  const unsigned short* __restrict__ hin,
                                                  const unsigned short* __restrict__ Bp,
                                                  const float* __restrict__ bias,
                                                  const float* __restrict__ gamma_l,
                                                  const float* __restrict__ beta_l,
                                                  const float* __restrict__ w_src_next,  // null on last layer
                                                  unsigned short* __restrict__ hout,
                                                  unsigned char* __restrict__ f8out,     // null on last layer
                                                  float* __restrict__ e_out,
                                                  float* __restrict__ colsum) {          // non-null on last layer
    __shared__ __align__(16) unsigned char lds_raw[4 * 16 * LDS_STRIDE * 2];  // 33792 B
    unsigned short* bbuf0 = (unsigned short*)lds_raw;           // 16 KB
    unsigned short* bbuf1 = bbuf0 + 8192;                       // 16 KB
    int w = threadIdx.x >> 6, lane = threadIdx.x & 63;
    int c = lane & 15, q = lane >> 4;
    int m0 = blockIdx.x * 64 + w * 16;

    // ================= phase 1: aggregate rows m0..m0+15 =================
    {
        const int g16 = lane >> 4;           // edge-quad group 0..3
        const int col16 = (lane & 15) * 16;
        for (int i = 0; i < 16; ++i) {
            int n = m0 + i;
            if (n >= NN) break;
            int deg = cursor[n];             // padded & clamped
            const unsigned short* row = csr + (size_t)n * CAP;

            float acc[16];
            #pragma unroll
            for (int j = 0; j < 16; ++j) acc[j] = 0.f;
            float den = 0.f;

            uint2 iw = make_uint2(0u, 0u);
            if (deg > 0) iw = *reinterpret_cast<const uint2*>(row + 4 * g16);

            #pragma unroll 2
            for (int p = 0; p + 16 <= deg; p += 16) {
                int np = p + 16;
                uint2 iw_n = *reinterpret_cast<const uint2*>(
                    row + ((np + 16 <= deg) ? np : 0) + 4 * g16);
                int s0 = iw.x & 0xFFFF, s1 = iw.x >> 16;
                int s2 = iw.y & 0xFFFF, s3 = iw.y >> 16;
                float w0 = e_in[s0], w1 = e_in[s1], w2 = e_in[s2], w3 = e_in[s3];
                uint4 r0 = *reinterpret_cast<const uint4*>(f8 + (size_t)s0 * DIM + col16);
                uint4 r1 = *reinterpret_cast<const uint4*>(f8 + (size_t)s1 * DIM + col16);
                uint4 r2 = *reinterpret_cast<const uint4*>(f8 + (size_t)s2 * DIM + col16);
                uint4 r3 = *reinterpret_cast<const uint4*>(f8 + (size_t)s3 * DIM + col16);
                fp8x16_fma(acc, r0, w0);
                fp8x16_fma(acc, r1, w1);
                fp8x16_fma(acc, r2, w2);
                fp8x16_fma(acc, r3, w3);
                den += (w0 + w1) + (w2 + w3);
                iw = iw_n;
            }

            den += __shfl_xor(den, 16);
            den += __shfl_xor(den, 32);
            float inv = (den > 0.f) ? 1.f / den : 0.f;
            #pragma unroll
            for (int j = 0; j < 16; ++j) {
                acc[j] += __shfl_xor(acc[j], 16);
                acc[j] += __shfl_xor(acc[j], 32);
            }

            if (g16 == 0) {
                bf16x8 o0, o1;
                #pragma unroll
                for (int j = 0; j < 8; ++j) {
                    o0[j] = (short)f2bf(acc[j] * inv);
                    o1[j] = (short)f2bf(acc[j + 8] * inv);
                }
                *reinterpret_cast<bf16x8*>(aggbuf + (size_t)n * DIM + col16) = o0;
                *reinterpret_cast<bf16x8*>(aggbuf + (size_t)n * DIM + col16 + 8) = o1;
            }
        }
        // same-wave RAW: agg stores must reach L2 before phase-2 reads them back
        asm volatile("s_waitcnt vmcnt(0)" ::: "memory");
    }

    // ================= phase 2: MFMA GEMM + LN + ReLU + packs =================
    auto stage = [&](int ks, unsigned short* buf) {
        const unsigned short* g = Bp + (size_t)ks * 8192 + w * 2048 + lane * 8;
        unsigned short* l = buf + w * 2048;   // wave-uniform base
        #pragma unroll
        for (int i = 0; i < 4; ++i)
            gload_lds16(g + i * 512, l + i * 512);
    };

    f32x4 acc[16];
    #pragma unroll
    for (int nf = 0; nf < 16; ++nf) {
        float b = bias[nf * 16 + c];
        acc[nf] = (f32x4){b, b, b, b};
    }

    stage(0, bbuf0);
    bf16x8 a_cur = *reinterpret_cast<const bf16x8*>(hin + (size_t)(m0 + c) * DIM + q * 8);
    __syncthreads();

    #pragma unroll
    for (int ks = 0; ks < 16; ++ks) {
        const unsigned short* bb = (ks & 1) ? bbuf1 : bbuf0;
        unsigned short* bnext    = (ks & 1) ? bbuf0 : bbuf1;
        bf16x8 a_next = a_cur;
        if (ks + 1 < 16) {
            stage(ks + 1, bnext);
            const int kk1 = (ks + 1) * 32;
            const unsigned short* hs = (kk1 < DIM) ? hin : aggbuf;
            a_next = *reinterpret_cast<const bf16x8*>(
                hs + (size_t)(m0 + c) * DIM + (kk1 & (DIM - 1)) + q * 8);
        }
        #pragma unroll
        for (int nf = 0; nf < 16; ++nf) {
            bf16x8 bfr = *reinterpret_cast<const bf16x8*>(bb + nf * 512 + lane * 8);
            acc[nf] = __builtin_amdgcn_mfma_f32_16x16x32_bf16(a_cur, bfr, acc[nf], 0, 0, 0);
        }
        __syncthreads();
        a_cur = a_next;
    }

    // LN + ReLU + next-layer score
    #pragma unroll
    for (int r = 0; r < 4; ++r) {
        float s = 0.f, s2 = 0.f;
        #pragma unroll
        for (int nf = 0; nf < 16; ++nf) {
            float v = acc[nf][r];
            s += v; s2 += v * v;
        }
        #pragma unroll
        for (int msk = 1; msk < 16; msk <<= 1) {
            s  += __shfl_xor(s, msk);
            s2 += __shfl_xor(s2, msk);
        }
        float mu = s * (1.f / DIM);
        float var = s2 * (1.f / DIM) - mu * mu;
        float rstd = rsqrtf(var + 1e-5f);
        float sc = 0.f;
        #pragma unroll
        for (int nf = 0; nf < 16; ++nf) {
            float v = fmaxf(gamma_l[nf * 16 + c] * (acc[nf][r] - mu) * rstd + beta_l[nf * 16 + c], 0.f);
            acc[nf][r] = v;
            if (w_src_next) sc += v * w_src_next[nf * 16 + c];
        }
        if (w_src_next) {
            #pragma unroll
            for (int msk = 1; msk < 16; msk <<= 1) sc += __shfl_xor(sc, msk);
            int row = m0 + q * 4 + r;
            if (c == 0 && row < NN) e_out[row] = __expf(sc);
        }
    }

    // pack 16 rows via per-wave LDS staging (aliases B buffers)
    unsigned short* myl = (unsigned short*)lds_raw + w * 16 * LDS_STRIDE;
    #pragma unroll
    for (int nf = 0; nf < 16; ++nf) {
        #pragma unroll
        for (int r = 0; r < 4; ++r)
            myl[(q * 4 + r) * LDS_STRIDE + nf * 16 + c] = f2bf(acc[nf][r]);
    }
    #pragma unroll
    for (int i = 0; i < 8; ++i) {
        int row16 = 2 * i + (lane >> 5);
        bf16x8 v = *reinterpret_cast<const bf16x8*>(myl + row16 * LDS_STRIDE + (lane & 31) * 8);
        int grow = m0 + row16;
        if (grow < NN) {
            *reinterpret_cast<bf16x8*>(hout + (size_t)grow * DIM + (lane & 31) * 8) = v;
            if (f8out) {
                uint2 pk;
                pk.x = fp8x4_enc(bf2f((unsigned short)v[0]), bf2f((unsigned short)v[1]),
                                 bf2f((unsigned short)v[2]), bf2f((unsigned short)v[3]));
                pk.y = fp8x4_enc(bf2f((unsigned short)v[4]), bf2f((unsigned short)v[5]),
                                 bf2f((unsigned short)v[6]), bf2f((unsigned short)v[7]));
                *reinterpret_cast<uint2*>(f8out + (size_t)grow * DIM + (lane & 31) * 8) = pk;
            }
        }
    }

    // fused column-sum of the output rows (last layer only): LDS repack buffer holds them
    if (colsum) {
        __syncthreads();
        int t = threadIdx.x;
        float s = 0.f;
        unsigned short* l0 = (unsigned short*)lds_raw;
        #pragma unroll 4
        for (int r = 0; r < 64; ++r) {
            if (blockIdx.x * 64 + r < NN)
                s += bf2f(l0[((r >> 4) * 16 + (r & 15)) * LDS_STRIDE + t]);
        }
        atomicAdd(&colsum[t], s);
    }
}

// ---------------- column sum (fp32 input) ----------------
__global__ __launch_bounds__(256) void k_colsum_f32(const float* __restrict__ mat, float* __restrict__ out) {
    int j = threadIdx.x;
    float s = 0.f;
    for (int r = blockIdx.x; r < NN; r += gridDim.x) s += mat[(size_t)r * DIM + j];
    atomicAdd(&out[j], s);
}

// ---------------- final: out = mean(h) + mean(x) @ W_skip + b_skip ----------------
__global__ __launch_bounds__(256) void k_final(const float* __restrict__ hsum, const float* __restrict__ xsum,
                                               const float* __restrict__ W_skip, const float* __restrict__ b_skip,
                                               float* __restrict__ out) {
    int j = threadIdx.x;
    float acc = 0.f;
    const float invN = 1.f / (float)NN;
    for (int i = 0; i < DIM; ++i) acc += (xsum[i] * invN) * W_skip[(size_t)i * DIM + j];
    out[j] = hsum[j] * invN + acc + b_skip[j];
}

extern "C" void kernel_launch(void* const* d_in, const int* in_sizes, int n_in,
                              void* d_out, int out_size, void* d_ws, size_t ws_size,
                              hipStream_t stream) {
    const float* x      = (const float*)d_in[0];
    const int*   ei     = (const int*)d_in[1];
    const float* W_sage = (const float*)d_in[2];
    const float* b_sage = (const float*)d_in[3];
    const float* gamma  = (const float*)d_in[4];
    const float* beta   = (const float*)d_in[5];
    const float* W_attn = (const float*)d_in[6];
    // d_in[7] = b_attn: cancels in the per-dst softmax — unused.
    const float* W_skip = (const float*)d_in[8];
    const float* b_skip = (const float*)d_in[9];
    float* out = (float*)d_out;

    // ---- workspace layout ----
    const size_t ND = (size_t)NN * DIM;
    unsigned short* hx   = (unsigned short*)d_ws;        // ND bf16
    unsigned short* hA   = hx + ND;                      // ND bf16
    unsigned short* hB   = hA + ND;                      // ND bf16
    unsigned short* agg  = hB + ND;                      // ND bf16 (block-private scratch)
    unsigned short* Bp   = agg + ND;                     // 512*256 bf16
    unsigned char*  f8a  = (unsigned char*)(Bp + (size_t)KDIM * DIM + 64);  // ND+DIM fp8 (+zero row)
    unsigned char*  f8b  = f8a + ND + DIM;               // ND+DIM fp8 (+zero row)
    float* e_a    = (float*)(f8b + ND + DIM + 64);       // NN+16 (sentinel at [NN])
    float* e_b    = e_a + NN + 16;                       // NN+16 (sentinel at [NN])
    float* colsum = e_b + NN + 16;                       // DIM
    float* xsum   = colsum + DIM;                        // DIM
    int*   cursor = (int*)(xsum + DIM);                  // NN degree counters
    unsigned short* csr = (unsigned short*)(cursor + NN);  // NN*CAP ushorts (8 MB)

    const int NBLK_RANGED = NRANGE * 784;  // 8 ranges x 784 stride-blocks
    const int NBLK_N = (NN + 255) / 256;   // 196
    const int NBLK_G = (NN + 63) / 64;     // 782 fused blocks

    hipError_t err;
    err = hipMemsetAsync(cursor, 0, (size_t)NN * sizeof(int), stream); (void)err;
    err = hipMemsetAsync(colsum, 0, 2 * DIM * sizeof(float), stream); (void)err;
    err = hipMemsetAsync(f8a + ND, 0, DIM, stream); (void)err;              // zero fp8 sentinel row
    err = hipMemsetAsync(f8b + ND, 0, DIM, stream); (void)err;              // zero fp8 sentinel row
    err = hipMemsetAsync(e_a + NN, 0, sizeof(float), stream); (void)err;    // sentinel weight 0
    err = hipMemsetAsync(e_b + NN, 0, sizeof(float), stream); (void)err;    // sentinel weight 0

    // CSR build: single scatter pass + pad rows to multiple of 16 with sentinel edges
    k_scatter<<<NBLK_RANGED, 256, 0, stream>>>(ei, cursor, csr);
    k_pad<<<NBLK_N, 256, 0, stream>>>(cursor, csr);

    // x -> bf16 + fp8 + layer-0 scores (into e_a)
    k_prep<<<NN / 4, 256, 0, stream>>>(x, W_attn + DIM, hx, f8a, e_a);

    // xsum (independent of the layer chain)
    k_colsum_f32<<<256, 256, 0, stream>>>(x, xsum);

    unsigned short* hbufs[4]  = {hx, hA, hB, hA};   // layer l reads hbufs[l], writes hbufs[l+1]
    unsigned char*  f8bufs[3] = {f8a, f8b, f8a};    // layer l reads f8bufs[l], writes f8bufs[l+1 mod]
    float*          ebufs[2]  = {e_a, e_b};         // layer l reads ebufs[l&1], writes ebufs[(l+1)&1]
    for (int l = 0; l < NLAYER; ++l) {
        k_packB<<<(KDIM * DIM) / 256, 256, 0, stream>>>(W_sage + (size_t)l * KDIM * DIM, Bp);
        const bool last = (l == NLAYER - 1);
        const float* wnext = last ? nullptr : (W_attn + (size_t)(l + 1) * KDIM + DIM);
        unsigned char* f8next = last ? nullptr : f8bufs[l + 1];
        k_agg_gemm<<<NBLK_G, 256, 0, stream>>>(
            f8bufs[l], ebufs[l & 1], cursor, csr, agg,
            hbufs[l], Bp, b_sage + (size_t)l * DIM,
            gamma + (size_t)l * DIM, beta + (size_t)l * DIM,
            wnext, hbufs[l + 1], f8next, ebufs[(l + 1) & 1],
            last ? colsum : nullptr);
    }

    k_final<<<1, 256, 0, stream>>>(colsum, xsum, W_skip, b_skip, out);
}

// Round 16
// 536.870 us; speedup vs baseline: 1.0475x; 1.0475x over previous
//
#include <hip/hip_runtime.h>
#include <hip/hip_bf16.h>

#define NN 50000
#define EE 1600000
#define DIM 256
#define KDIM 512
#define NLAYER 3
#define NRANGE 8
#define RNODES (NN / NRANGE)   // 6250
#define CAP 80                 // fixed CSR row capacity (multiple of 16); P(deg>80) ~ 1e-17

using bf16x8 = __attribute__((ext_vector_type(8))) short;
using f32x4  = __attribute__((ext_vector_type(4))) float;
using f32x2  = __attribute__((ext_vector_type(2))) float;

static __device__ __forceinline__ unsigned short f2bf(float f) {
    unsigned u = __builtin_bit_cast(unsigned, f);
    unsigned r = (u + 0x7FFFu + ((u >> 16) & 1u)) >> 16;   // RNE
    return (unsigned short)r;
}
static __device__ __forceinline__ float bf2f(unsigned short s) {
    return __builtin_bit_cast(float, (unsigned)s << 16);
}

// ---- async global->LDS, 16B per lane. LDS dest is wave-uniform base + lane*16 (G21).
static __device__ __forceinline__ void gload_lds16(const void* g, void* l) {
    __builtin_amdgcn_global_load_lds(
        reinterpret_cast<const __attribute__((address_space(1))) void*>(
            reinterpret_cast<uintptr_t>(g)),
        reinterpret_cast<__attribute__((address_space(3))) void*>(
            static_cast<unsigned>(reinterpret_cast<uintptr_t>(l))),
        16, 0, 0);
}

// ---- fp8 e4m3 (OCP) helpers ----
#if defined(__has_builtin) && __has_builtin(__builtin_amdgcn_cvt_pk_f32_fp8) && __has_builtin(__builtin_amdgcn_cvt_pk_fp8_f32)
#define FP8_NATIVE 1
#else
#define FP8_NATIVE 0
#endif

template <bool HI>
static __device__ __forceinline__ f32x2 fp8x2_dec(unsigned w) {
#if FP8_NATIVE
    return __builtin_amdgcn_cvt_pk_f32_fp8((int)w, HI);
#else
    unsigned v = HI ? (w >> 16) : w;
    unsigned b0 = v & 0xFFu, b1 = (v >> 8) & 0xFFu;
    unsigned u0 = ((b0 & 0x80u) << 24) | ((b0 & 0x7Fu) << 20);
    unsigned u1 = ((b1 & 0x80u) << 24) | ((b1 & 0x7Fu) << 20);
    f32x2 r;
    r[0] = __builtin_bit_cast(float, u0) * 0x1p120f;
    r[1] = __builtin_bit_cast(float, u1) * 0x1p120f;
    return r;
#endif
}

#if !FP8_NATIVE
static __device__ __forceinline__ unsigned fp8_enc1(float f) {
    unsigned u = __builtin_bit_cast(unsigned, f * 0x1p-120f);
    unsigned s = (u >> 24) & 0x80u;
    unsigned m = u & 0x7FFFFFFFu;
    m = m + 0x7FFFFu + ((m >> 20) & 1u);
    return s | ((m >> 20) & 0x7Fu);
}
#endif

static __device__ __forceinline__ unsigned fp8x4_enc(float a, float b, float c, float d) {
#if FP8_NATIVE
    int w = __builtin_amdgcn_cvt_pk_fp8_f32(a, b, 0, false);
    w = __builtin_amdgcn_cvt_pk_fp8_f32(c, d, w, true);
    return (unsigned)w;
#else
    return fp8_enc1(a) | (fp8_enc1(b) << 8) | (fp8_enc1(c) << 16) | (fp8_enc1(d) << 24);
#endif
}

static __device__ __forceinline__ void fp8x8_fma(float* acc, unsigned lo, unsigned hi, float wg) {
    f32x2 p0 = fp8x2_dec<false>(lo);
    f32x2 p1 = fp8x2_dec<true>(lo);
    f32x2 p2 = fp8x2_dec<false>(hi);
    f32x2 p3 = fp8x2_dec<true>(hi);
    acc[0] += wg * p0[0]; acc[1] += wg * p0[1];
    acc[2] += wg * p1[0]; acc[3] += wg * p1[1];
    acc[4] += wg * p2[0]; acc[5] += wg * p2[1];
    acc[6] += wg * p3[0]; acc[7] += wg * p3[1];
}

static __device__ __forceinline__ void fp8x16_fma(float* acc, uint4 r, float wg) {
    fp8x8_fma(acc, r.x, r.y, wg);
    fp8x8_fma(acc + 8, r.z, r.w, wg);
}

// ---------------- prep: x (fp32) -> h0 (bf16 + fp8), e_src0 = exp(x . w_src0) ----------------
__global__ __launch_bounds__(256) void k_prep(const float* __restrict__ x,
                                              const float* __restrict__ w_src,
                                              unsigned short* __restrict__ hout,
                                              unsigned char* __restrict__ f8out,
                                              float* __restrict__ e_src) {
    int wave = threadIdx.x >> 6, lane = threadIdx.x & 63;
    int n = blockIdx.x * 4 + wave;
    if (n >= NN) return;
    const float4 v = *reinterpret_cast<const float4*>(x + (size_t)n * DIM + lane * 4);
    const float4 wv = *reinterpret_cast<const float4*>(w_src + lane * 4);
    float sc = v.x * wv.x + v.y * wv.y + v.z * wv.z + v.w * wv.w;
    #pragma unroll
    for (int m = 32; m; m >>= 1) sc += __shfl_xor(sc, m);
    if (lane == 0) e_src[n] = __expf(sc);
    ushort4 o;
    o.x = f2bf(v.x); o.y = f2bf(v.y); o.z = f2bf(v.z); o.w = f2bf(v.w);
    *reinterpret_cast<ushort4*>(hout + (size_t)n * DIM + lane * 4) = o;
    *reinterpret_cast<unsigned*>(f8out + (size_t)n * DIM + lane * 4) =
        fp8x4_enc(v.x, v.y, v.z, v.w);
}

// ---------------- CSR build: single range-partitioned scatter into fixed-CAP rows ----------
__global__ __launch_bounds__(256) void k_scatter(const int* __restrict__ ei, int* __restrict__ cursor,
                                                 unsigned short* __restrict__ csr) {
    const int range = blockIdx.x & (NRANGE - 1);
    const int lo = range * RNODES, hi = lo + RNODES;
    const int stride = (gridDim.x >> 3) * 256;
    for (int e = (blockIdx.x >> 3) * 256 + threadIdx.x; e < EE; e += stride) {
        int d = ei[EE + e];
        if (d >= lo && d < hi) {
            int pos = atomicAdd(&cursor[d], 1);
            if (pos < CAP) csr[d * CAP + pos] = (unsigned short)ei[e];
        }
    }
}

// ---------------- pad rows to multiple of 16 with sentinel edges (index NN: zero row) ------
__global__ __launch_bounds__(256) void k_pad(int* __restrict__ cursor,
                                             unsigned short* __restrict__ csr) {
    int n = blockIdx.x * 256 + threadIdx.x;
    if (n >= NN) return;
    int deg = cursor[n];
    if (deg > CAP) deg = CAP;
    int padded = (deg + 15) & ~15;
    if (padded > CAP) padded = CAP;
    for (int p = deg; p < padded; ++p) csr[(size_t)n * CAP + p] = (unsigned short)NN;
    cursor[n] = padded;
}

// ---------------- attention aggregation: quarter-wave per edge, 16 edges/wave-iter ----------
__global__ __launch_bounds__(256) void k_aggregate(const unsigned char* __restrict__ f8,
                                                   const float* __restrict__ e_src,
                                                   const int* __restrict__ cursor,
                                                   const unsigned short* __restrict__ csr,
                                                   unsigned short* __restrict__ agg) {
    int wave = threadIdx.x >> 6, lane = threadIdx.x & 63;
    int n = blockIdx.x * 4 + wave;
    if (n >= NN) return;
    int deg = cursor[n];               // padded & clamped
    const unsigned short* row = csr + (size_t)n * CAP;
    const int g = lane >> 4;           // group 0..3 (4 edges each per batch)
    const int col16 = (lane & 15) * 16;

    float acc[16];
    #pragma unroll
    for (int j = 0; j < 16; ++j) acc[j] = 0.f;
    float den = 0.f;

    uint2 iw = make_uint2(0u, 0u);
    if (deg > 0) iw = *reinterpret_cast<const uint2*>(row + 4 * g);

    #pragma unroll 2
    for (int p = 0; p + 16 <= deg; p += 16) {
        int np = p + 16;
        uint2 iw_n = *reinterpret_cast<const uint2*>(
            row + ((np + 16 <= deg) ? np : 0) + 4 * g);
        int s0 = iw.x & 0xFFFF, s1 = iw.x >> 16;
        int s2 = iw.y & 0xFFFF, s3 = iw.y >> 16;
        float w0 = e_src[s0], w1 = e_src[s1], w2 = e_src[s2], w3 = e_src[s3];
        uint4 r0 = *reinterpret_cast<const uint4*>(f8 + (size_t)s0 * DIM + col16);
        uint4 r1 = *reinterpret_cast<const uint4*>(f8 + (size_t)s1 * DIM + col16);
        uint4 r2 = *reinterpret_cast<const uint4*>(f8 + (size_t)s2 * DIM + col16);
        uint4 r3 = *reinterpret_cast<const uint4*>(f8 + (size_t)s3 * DIM + col16);
        fp8x16_fma(acc, r0, w0);
        fp8x16_fma(acc, r1, w1);
        fp8x16_fma(acc, r2, w2);
        fp8x16_fma(acc, r3, w3);
        den += (w0 + w1) + (w2 + w3);
        iw = iw_n;
    }

    den += __shfl_xor(den, 16);
    den += __shfl_xor(den, 32);
    float inv = (den > 0.f) ? 1.f / den : 0.f;
    #pragma unroll
    for (int j = 0; j < 16; ++j) {
        acc[j] += __shfl_xor(acc[j], 16);
        acc[j] += __shfl_xor(acc[j], 32);
    }

    if (g == 0) {
        bf16x8 o0, o1;
        #pragma unroll
        for (int j = 0; j < 8; ++j) {
            o0[j] = (short)f2bf(acc[j] * inv);
            o1[j] = (short)f2bf(acc[j + 8] * inv);
        }
        *reinterpret_cast<bf16x8*>(agg + (size_t)n * DIM + col16) = o0;
        *reinterpret_cast<bf16x8*>(agg + (size_t)n * DIM + col16 + 8) = o1;
    }
}

// ---------------- pack W (fp32 [512][256]) -> Bp bf16, lane-linear MFMA-B fragments ---------
__global__ __launch_bounds__(256) void k_packB(const float* __restrict__ W, unsigned short* __restrict__ Bp) {
    int tid = blockIdx.x * 256 + threadIdx.x;
    int j    = tid & 7;
    int lane = (tid >> 3) & 63;
    int nf   = (tid >> 9) & 15;
    int ks   = tid >> 13;
    int c = lane & 15, q = lane >> 4;
    Bp[tid] = f2bf(W[(size_t)(ks * 32 + q * 8 + j) * DIM + nf * 16 + c]);
}

// ---------------- fused MFMA GEMM + LN + ReLU + score + packs; triple-buffered B with
// counted-vmcnt barriers (stage 2 K-steps ahead; never drain vmcnt to 0 in the loop) -------
#define LDS_STRIDE 264
__global__ __launch_bounds__(256) void k_gemm_ln(const unsigned short* __restrict__ hin,
                                                 const unsigned short* __restrict__ agg,
                                                 const unsigned short* __restrict__ Bp,
                                                 const float* __restrict__ bias,
                                                 const float* __restrict__ gamma_l,
                                                 const float* __restrict__ beta_l,
                                                 const float* __restrict__ w_src_next,  // may be null
                                                 unsigned short* __restrict__ hout,
                                                 unsigned char* __restrict__ f8out,     // may be null
                                                 float* __restrict__ e_src) {
    __shared__ __align__(16) unsigned short lds_b[3 * 8192];   // 48 KB: 3 x 16KB B tiles
    int w = threadIdx.x >> 6, lane = threadIdx.x & 63;
    int c = lane & 15, q = lane >> 4;
    int m0 = blockIdx.x * 64 + w * 16;

    auto stage = [&](int ks, unsigned short* buf) {
        const unsigned short* g = Bp + (size_t)ks * 8192 + w * 2048 + lane * 8;
        unsigned short* l = buf + w * 2048;   // wave-uniform base
        #pragma unroll
        for (int i = 0; i < 4; ++i)
            gload_lds16(g + i * 512, l + i * 512);
    };

    f32x4 acc[16];
    #pragma unroll
    for (int nf = 0; nf < 16; ++nf) {
        float b = bias[nf * 16 + c];
        acc[nf] = (f32x4){b, b, b, b};
    }

    // prologue: stage 0 and 1; load A(0). Outstanding: 4+4+1 -> wait for stage(0): vmcnt(5).
    stage(0, lds_b);
    stage(1, lds_b + 8192);
    bf16x8 a_cur = *reinterpret_cast<const bf16x8*>(hin + (size_t)(m0 + c) * DIM + q * 8);
    asm volatile("s_waitcnt vmcnt(5)\n\ts_barrier" ::: "memory");

    #pragma unroll
    for (int ks = 0; ks < 16; ++ks) {
        const unsigned short* bb = lds_b + (ks % 3) * 8192;
        if (ks + 2 < 16) stage(ks + 2, lds_b + ((ks + 2) % 3) * 8192);
        bf16x8 a_next = a_cur;
        if (ks + 1 < 16) {
            const int kk1 = (ks + 1) * 32;
            const unsigned short* hs = (kk1 < DIM) ? hin : agg;
            a_next = *reinterpret_cast<const bf16x8*>(
                hs + (size_t)(m0 + c) * DIM + (kk1 & (DIM - 1)) + q * 8);
        }
        #pragma unroll
        for (int nf = 0; nf < 16; ++nf) {
            bf16x8 bfr = *reinterpret_cast<const bf16x8*>(bb + nf * 512 + lane * 8);
            acc[nf] = __builtin_amdgcn_mfma_f32_16x16x32_bf16(a_cur, bfr, acc[nf], 0, 0, 0);
        }
        // end-of-step barrier with counted vmcnt: stage(ks+1) (issued last iter) must be
        // complete; the newest loads (stage(ks+2)=4, a_next=1) stay in flight.
        if (ks <= 13) {
            asm volatile("s_waitcnt vmcnt(5)\n\ts_barrier" ::: "memory");
        } else if (ks == 14) {
            asm volatile("s_waitcnt vmcnt(1)\n\ts_barrier" ::: "memory");   // only a_next(15) in flight
        } else {
            asm volatile("s_barrier" ::: "memory");                          // before epilogue LDS reuse
        }
        a_cur = a_next;
    }

    // LN + ReLU + next-layer score
    #pragma unroll
    for (int r = 0; r < 4; ++r) {
        float s = 0.f, s2 = 0.f;
        #pragma unroll
        for (int nf = 0; nf < 16; ++nf) {
            float v = acc[nf][r];
            s += v; s2 += v * v;
        }
        #pragma unroll
        for (int msk = 1; msk < 16; msk <<= 1) {
            s  += __shfl_xor(s, msk);
            s2 += __shfl_xor(s2, msk);
        }
        float mu = s * (1.f / DIM);
        float var = s2 * (1.f / DIM) - mu * mu;
        float rstd = rsqrtf(var + 1e-5f);
        float sc = 0.f;
        #pragma unroll
        for (int nf = 0; nf < 16; ++nf) {
            float v = fmaxf(gamma_l[nf * 16 + c] * (acc[nf][r] - mu) * rstd + beta_l[nf * 16 + c], 0.f);
            acc[nf][r] = v;
            if (w_src_next) sc += v * w_src_next[nf * 16 + c];
        }
        if (w_src_next) {
            #pragma unroll
            for (int msk = 1; msk < 16; msk <<= 1) sc += __shfl_xor(sc, msk);
            int row = m0 + q * 4 + r;
            if (c == 0 && row < NN) e_src[row] = __expf(sc);
        }
    }

    // pack 16 rows via per-wave LDS staging (aliases B buffers; loop fully barriered)
    unsigned short* myl = lds_b + w * 16 * LDS_STRIDE;
    #pragma unroll
    for (int nf = 0; nf < 16; ++nf) {
        #pragma unroll
        for (int r = 0; r < 4; ++r)
            myl[(q * 4 + r) * LDS_STRIDE + nf * 16 + c] = f2bf(acc[nf][r]);
    }
    #pragma unroll
    for (int i = 0; i < 8; ++i) {
        int row16 = 2 * i + (lane >> 5);
        bf16x8 v = *reinterpret_cast<const bf16x8*>(myl + row16 * LDS_STRIDE + (lane & 31) * 8);
        int grow = m0 + row16;
        if (grow < NN) {
            *reinterpret_cast<bf16x8*>(hout + (size_t)grow * DIM + (lane & 31) * 8) = v;
            if (f8out) {
                uint2 pk;
                pk.x = fp8x4_enc(bf2f((unsigned short)v[0]), bf2f((unsigned short)v[1]),
                                 bf2f((unsigned short)v[2]), bf2f((unsigned short)v[3]));
                pk.y = fp8x4_enc(bf2f((unsigned short)v[4]), bf2f((unsigned short)v[5]),
                                 bf2f((unsigned short)v[6]), bf2f((unsigned short)v[7]));
                *reinterpret_cast<uint2*>(f8out + (size_t)grow * DIM + (lane & 31) * 8) = pk;
            }
        }
    }
}

// ---------------- column sums ----------------
__global__ __launch_bounds__(256) void k_colsum_f32(const float* __restrict__ mat, float* __restrict__ out) {
    int j = threadIdx.x;
    float s = 0.f;
    for (int r = blockIdx.x; r < NN; r += gridDim.x) s += mat[(size_t)r * DIM + j];
    atomicAdd(&out[j], s);
}
__global__ __launch_bounds__(256) void k_colsum_bf16(const unsigned short* __restrict__ mat,
                                                     float* __restrict__ out) {
    int j = threadIdx.x;
    float s = 0.f;
    for (int r = blockIdx.x; r < NN; r += gridDim.x) s += bf2f(mat[(size_t)r * DIM + j]);
    atomicAdd(&out[j], s);
}

// ---------------- final: out = mean(h) + mean(x) @ W_skip + b_skip ----------------
__global__ __launch_bounds__(256) void k_final(const float* __restrict__ hsum, const float* __restrict__ xsum,
                                               const float* __restrict__ W_skip, const float* __restrict__ b_skip,
                                               float* __restrict__ out) {
    int j = threadIdx.x;
    float acc = 0.f;
    const float invN = 1.f / (float)NN;
    for (int i = 0; i < DIM; ++i) acc += (xsum[i] * invN) * W_skip[(size_t)i * DIM + j];
    out[j] = hsum[j] * invN + acc + b_skip[j];
}

extern "C" void kernel_launch(void* const* d_in, const int* in_sizes, int n_in,
                              void* d_out, int out_size, void* d_ws, size_t ws_size,
                              hipStream_t stream) {
    const float* x      = (const float*)d_in[0];
    const int*   ei     = (const int*)d_in[1];
    const float* W_sage = (const float*)d_in[2];
    const float* b_sage = (const float*)d_in[3];
    const float* gamma  = (const float*)d_in[4];
    const float* beta   = (const float*)d_in[5];
    const float* W_attn = (const float*)d_in[6];
    // d_in[7] = b_attn: cancels in the per-dst softmax — unused.
    const float* W_skip = (const float*)d_in[8];
    const float* b_skip = (const float*)d_in[9];
    float* out = (float*)d_out;

    // ---- workspace layout ----
    const size_t ND = (size_t)NN * DIM;
    unsigned short* hx   = (unsigned short*)d_ws;        // ND bf16
    unsigned short* hA   = hx + ND;                      // ND bf16
    unsigned short* hB   = hA + ND;                      // ND bf16
    unsigned short* agg  = hB + ND;                      // ND bf16
    unsigned short* Bp   = agg + ND;                     // 512*256 bf16
    unsigned char*  f8a  = (unsigned char*)(Bp + (size_t)KDIM * DIM + 64);  // ND+DIM fp8 (+zero row)
    unsigned char*  f8b  = f8a + ND + DIM;               // ND+DIM fp8 (+zero row)
    float* e_src  = (float*)(f8b + ND + DIM + 64);       // NN+1 (sentinel weight at [NN])
    float* colsum = e_src + NN + 16;                     // DIM
    float* xsum   = colsum + DIM;                        // DIM
    int*   cursor = (int*)(xsum + DIM);                  // NN degree counters
    unsigned short* csr = (unsigned short*)(cursor + NN);  // NN*CAP ushorts (8 MB)

    const int NBLK_RANGED = NRANGE * 784;  // 8 ranges x 784 stride-blocks
    const int NBLK_N = (NN + 255) / 256;   // 196

    hipError_t err;
    err = hipMemsetAsync(cursor, 0, (size_t)NN * sizeof(int), stream); (void)err;
    err = hipMemsetAsync(colsum, 0, 2 * DIM * sizeof(float), stream); (void)err;
    err = hipMemsetAsync(f8a + ND, 0, DIM, stream); (void)err;        // zero fp8 row (sentinel)
    err = hipMemsetAsync(f8b + ND, 0, DIM, stream); (void)err;        // zero fp8 row (sentinel)
    err = hipMemsetAsync(e_src + NN, 0, sizeof(float), stream); (void)err;  // sentinel weight 0

    // CSR build: single scatter pass + pad rows to multiple of 16 with sentinel edges
    k_scatter<<<NBLK_RANGED, 256, 0, stream>>>(ei, cursor, csr);
    k_pad<<<NBLK_N, 256, 0, stream>>>(cursor, csr);

    // x -> bf16 + fp8 + layer-0 scores
    k_prep<<<NN / 4, 256, 0, stream>>>(x, W_attn + DIM, hx, f8a, e_src);

    unsigned short* hbufs[3] = {hx, hA, hB};
    unsigned char*  f8bufs[3] = {f8a, f8b, f8a};   // ping-pong; layer 2 output unused
    for (int l = 0; l < NLAYER; ++l) {
        unsigned short* h_in  = hbufs[l];
        unsigned short* h_out = hbufs[l + 1 < 3 ? l + 1 : 1];  // l=2 -> hA
        k_packB<<<(KDIM * DIM) / 256, 256, 0, stream>>>(W_sage + (size_t)l * KDIM * DIM, Bp);
        k_aggregate<<<NN / 4, 256, 0, stream>>>(f8bufs[l], e_src, cursor, csr, agg);
        const float* wnext = (l < NLAYER - 1) ? (W_attn + (size_t)(l + 1) * KDIM + DIM) : nullptr;
        unsigned char* f8next = (l < NLAYER - 1) ? f8bufs[l + 1] : nullptr;
        k_gemm_ln<<<(NN + 63) / 64, 256, 0, stream>>>(
            h_in, agg, Bp, b_sage + (size_t)l * DIM,
            gamma + (size_t)l * DIM, beta + (size_t)l * DIM,
            wnext, h_out, f8next, e_src);
    }

    k_colsum_bf16<<<256, 256, 0, stream>>>(hbufs[1], colsum);  // final h lives in hA
    k_colsum_f32<<<256, 256, 0, stream>>>(x, xsum);
    k_final<<<1, 256, 0, stream>>>(colsum, xsum, W_skip, b_skip, out);
}

// Round 17
// 497.984 us; speedup vs baseline: 1.1293x; 1.0781x over previous
//
#include <hip/hip_runtime.h>
#include <hip/hip_bf16.h>

#define NN 50000
#define EE 1600000
#define DIM 256
#define KDIM 512
#define NLAYER 3
#define NRANGE 8
#define RNODES (NN / NRANGE)   // 6250
#define CAP 80                 // fixed CSR row capacity; P(deg>80) ~ 1e-17 per node

using bf16x8 = __attribute__((ext_vector_type(8))) short;
using f32x4  = __attribute__((ext_vector_type(4))) float;
using f32x2  = __attribute__((ext_vector_type(2))) float;

static __device__ __forceinline__ unsigned short f2bf(float f) {
    unsigned u = __builtin_bit_cast(unsigned, f);
    unsigned r = (u + 0x7FFFu + ((u >> 16) & 1u)) >> 16;   // RNE
    return (unsigned short)r;
}
static __device__ __forceinline__ float bf2f(unsigned short s) {
    return __builtin_bit_cast(float, (unsigned)s << 16);
}

// ---- async global->LDS, 16B per lane. LDS dest is wave-uniform base + lane*16 (G21).
static __device__ __forceinline__ void gload_lds16(const void* g, void* l) {
    __builtin_amdgcn_global_load_lds(
        reinterpret_cast<const __attribute__((address_space(1))) void*>(
            reinterpret_cast<uintptr_t>(g)),
        reinterpret_cast<__attribute__((address_space(3))) void*>(
            static_cast<unsigned>(reinterpret_cast<uintptr_t>(l))),
        16, 0, 0);
}

// ---- fp8 e4m3 (OCP) helpers ----
#if defined(__has_builtin) && __has_builtin(__builtin_amdgcn_cvt_pk_f32_fp8) && __has_builtin(__builtin_amdgcn_cvt_pk_fp8_f32)
#define FP8_NATIVE 1
#else
#define FP8_NATIVE 0
#endif

template <bool HI>
static __device__ __forceinline__ f32x2 fp8x2_dec(unsigned w) {
#if FP8_NATIVE
    return __builtin_amdgcn_cvt_pk_f32_fp8((int)w, HI);
#else
    unsigned v = HI ? (w >> 16) : w;
    unsigned b0 = v & 0xFFu, b1 = (v >> 8) & 0xFFu;
    unsigned u0 = ((b0 & 0x80u) << 24) | ((b0 & 0x7Fu) << 20);
    unsigned u1 = ((b1 & 0x80u) << 24) | ((b1 & 0x7Fu) << 20);
    f32x2 r;
    r[0] = __builtin_bit_cast(float, u0) * 0x1p120f;
    r[1] = __builtin_bit_cast(float, u1) * 0x1p120f;
    return r;
#endif
}

#if !FP8_NATIVE
static __device__ __forceinline__ unsigned fp8_enc1(float f) {
    unsigned u = __builtin_bit_cast(unsigned, f * 0x1p-120f);
    unsigned s = (u >> 24) & 0x80u;
    unsigned m = u & 0x7FFFFFFFu;
    m = m + 0x7FFFFu + ((m >> 20) & 1u);
    return s | ((m >> 20) & 0x7Fu);
}
#endif

static __device__ __forceinline__ unsigned fp8x4_enc(float a, float b, float c, float d) {
#if FP8_NATIVE
    int w = __builtin_amdgcn_cvt_pk_fp8_f32(a, b, 0, false);
    w = __builtin_amdgcn_cvt_pk_fp8_f32(c, d, w, true);
    return (unsigned)w;
#else
    return fp8_enc1(a) | (fp8_enc1(b) << 8) | (fp8_enc1(c) << 16) | (fp8_enc1(d) << 24);
#endif
}

// decode 8 fp8 (uint2) scaled by wg into acc[0..7]
static __device__ __forceinline__ void fp8x8_fma(float* acc, uint2 r, float wg) {
    f32x2 p0 = fp8x2_dec<false>(r.x);
    f32x2 p1 = fp8x2_dec<true>(r.x);
    f32x2 p2 = fp8x2_dec<false>(r.y);
    f32x2 p3 = fp8x2_dec<true>(r.y);
    acc[0] += wg * p0[0]; acc[1] += wg * p0[1];
    acc[2] += wg * p1[0]; acc[3] += wg * p1[1];
    acc[4] += wg * p2[0]; acc[5] += wg * p2[1];
    acc[6] += wg * p3[0]; acc[7] += wg * p3[1];
}

// ---------------- prep: x (fp32) -> h0 (bf16 + fp8), e_src0 = exp(x . w_src0) ----------------
__global__ __launch_bounds__(256) void k_prep(const float* __restrict__ x,
                                              const float* __restrict__ w_src,
                                              unsigned short* __restrict__ hout,
                                              unsigned char* __restrict__ f8out,
                                              float* __restrict__ e_src) {
    int wave = threadIdx.x >> 6, lane = threadIdx.x & 63;
    int n = blockIdx.x * 4 + wave;
    if (n >= NN) return;
    const float4 v = *reinterpret_cast<const float4*>(x + (size_t)n * DIM + lane * 4);
    const float4 wv = *reinterpret_cast<const float4*>(w_src + lane * 4);
    float sc = v.x * wv.x + v.y * wv.y + v.z * wv.z + v.w * wv.w;
    #pragma unroll
    for (int m = 32; m; m >>= 1) sc += __shfl_xor(sc, m);
    if (lane == 0) e_src[n] = __expf(sc);
    ushort4 o;
    o.x = f2bf(v.x); o.y = f2bf(v.y); o.z = f2bf(v.z); o.w = f2bf(v.w);
    *reinterpret_cast<ushort4*>(hout + (size_t)n * DIM + lane * 4) = o;
    *reinterpret_cast<unsigned*>(f8out + (size_t)n * DIM + lane * 4) =
        fp8x4_enc(v.x, v.y, v.z, v.w);
}

// ---------------- CSR build: single range-partitioned scatter into fixed-CAP rows ----------
__global__ __launch_bounds__(256) void k_scatter(const int* __restrict__ ei, int* __restrict__ cursor,
                                                 unsigned short* __restrict__ csr) {
    const int range = blockIdx.x & (NRANGE - 1);
    const int lo = range * RNODES, hi = lo + RNODES;
    const int stride = (gridDim.x >> 3) * 256;
    for (int e = (blockIdx.x >> 3) * 256 + threadIdx.x; e < EE; e += stride) {
        int d = ei[EE + e];
        if (d >= lo && d < hi) {
            int pos = atomicAdd(&cursor[d], 1);
            if (pos < CAP) csr[d * CAP + pos] = (unsigned short)ei[e];
        }
    }
}

// ---------------- attention aggregation over fp8 rows: 8 edges per wave-iteration ----------
// half-wave h takes 4 consecutive edges; each half-wave covers a full 256-col row.
__global__ __launch_bounds__(256) void k_aggregate(const unsigned char* __restrict__ f8,
                                                   const float* __restrict__ e_src,
                                                   const int* __restrict__ cursor,
                                                   const unsigned short* __restrict__ csr,
                                                   unsigned short* __restrict__ agg) {
    int wave = threadIdx.x >> 6, lane = threadIdx.x & 63;
    int n = blockIdx.x * 4 + wave;
    if (n >= NN) return;
    int deg = cursor[n];
    if (deg > CAP) deg = CAP;
    const unsigned short* row = csr + (size_t)n * CAP;
    const int half = lane >> 5;
    const int col8 = (lane & 31) * 8;

    float acc[8] = {0.f, 0.f, 0.f, 0.f, 0.f, 0.f, 0.f, 0.f};
    float den = 0.f;

    int p = 0;
    #pragma unroll 2
    for (; p + 8 <= deg; p += 8) {
        int b = p + 4 * half;
        int s0 = row[b + 0];
        int s1 = row[b + 1];
        int s2 = row[b + 2];
        int s3 = row[b + 3];
        float w0 = e_src[s0], w1 = e_src[s1], w2 = e_src[s2], w3 = e_src[s3];
        uint2 r0 = *reinterpret_cast<const uint2*>(f8 + (size_t)s0 * DIM + col8);
        uint2 r1 = *reinterpret_cast<const uint2*>(f8 + (size_t)s1 * DIM + col8);
        uint2 r2 = *reinterpret_cast<const uint2*>(f8 + (size_t)s2 * DIM + col8);
        uint2 r3 = *reinterpret_cast<const uint2*>(f8 + (size_t)s3 * DIM + col8);
        fp8x8_fma(acc, r0, w0);
        fp8x8_fma(acc, r1, w1);
        fp8x8_fma(acc, r2, w2);
        fp8x8_fma(acc, r3, w3);
        den += (w0 + w1) + (w2 + w3);
    }
    for (; p < deg; p += 2) {
        int idx = p + half;
        bool valid = idx < deg;
        int s0 = row[valid ? idx : 0];
        float w0 = valid ? e_src[s0] : 0.f;
        uint2 r0 = *reinterpret_cast<const uint2*>(f8 + (size_t)s0 * DIM + col8);
        fp8x8_fma(acc, r0, w0);
        den += w0;
    }

    den += __shfl_xor(den, 32);
    float inv = (deg > 0 && den > 0.f) ? 1.f / den : 0.f;
    #pragma unroll
    for (int j = 0; j < 8; ++j) acc[j] += __shfl_xor(acc[j], 32);

    if (half == 0) {
        bf16x8 o;
        #pragma unroll
        for (int j = 0; j < 8; ++j) o[j] = (short)f2bf(acc[j] * inv);
        *reinterpret_cast<bf16x8*>(agg + (size_t)n * DIM + col8) = o;
    }
}

// ---------------- pack all 3 layers' W -> Bp3 bf16, lane-linear MFMA-B fragments ----------
// layer stride = KDIM*DIM = 131072 elements; 512 blocks per layer.
__global__ __launch_bounds__(256) void k_packB3(const float* __restrict__ W_all,
                                                unsigned short* __restrict__ Bp3) {
    int gid = blockIdx.x * 256 + threadIdx.x;
    int l   = gid >> 17;                 // 131072 elements per layer
    int tid = gid & 131071;
    int j    = tid & 7;
    int lane = (tid >> 3) & 63;
    int nf   = (tid >> 9) & 15;
    int ks   = tid >> 13;
    int c = lane & 15, q = lane >> 4;
    Bp3[gid] = f2bf(W_all[(size_t)l * KDIM * DIM + (size_t)(ks * 32 + q * 8 + j) * DIM + nf * 16 + c]);
}

// ---------------- fused MFMA GEMM + LN + ReLU + score + packs (+ colsum on last layer) -----
// Double-buffered LDS B staging (global_load_lds w=16); A prefetched 1 K-step ahead.
#define LDS_STRIDE 264
__global__ __launch_bounds__(256) void k_gemm_ln(const unsigned short* __restrict__ hin,
                                                 const unsigned short* __restrict__ agg,
                                                 const unsigned short* __restrict__ Bp,
                                                 const float* __restrict__ bias,
                                                 const float* __restrict__ gamma_l,
                                                 const float* __restrict__ beta_l,
                                                 const float* __restrict__ w_src_next,  // null on last layer
                                                 unsigned short* __restrict__ hout,
                                                 unsigned char* __restrict__ f8out,     // null on last layer
                                                 float* __restrict__ e_src,
                                                 float* __restrict__ colsum) {          // non-null on last layer
    __shared__ __align__(16) unsigned char lds_raw[4 * 16 * LDS_STRIDE * 2];  // 33792 B
    unsigned short* bbuf0 = (unsigned short*)lds_raw;           // 16 KB
    unsigned short* bbuf1 = bbuf0 + 8192;                       // 16 KB
    int w = threadIdx.x >> 6, lane = threadIdx.x & 63;
    int c = lane & 15, q = lane >> 4;
    int m0 = blockIdx.x * 64 + w * 16;

    auto stage = [&](int ks, unsigned short* buf) {
        const unsigned short* g = Bp + (size_t)ks * 8192 + w * 2048 + lane * 8;
        unsigned short* l = buf + w * 2048;   // wave-uniform base
        #pragma unroll
        for (int i = 0; i < 4; ++i)
            gload_lds16(g + i * 512, l + i * 512);
    };

    f32x4 acc[16];
    #pragma unroll
    for (int nf = 0; nf < 16; ++nf) {
        float b = bias[nf * 16 + c];
        acc[nf] = (f32x4){b, b, b, b};
    }

    stage(0, bbuf0);
    bf16x8 a_cur = *reinterpret_cast<const bf16x8*>(hin + (size_t)(m0 + c) * DIM + q * 8);
    __syncthreads();

    #pragma unroll
    for (int ks = 0; ks < 16; ++ks) {
        const unsigned short* bb = (ks & 1) ? bbuf1 : bbuf0;
        unsigned short* bnext    = (ks & 1) ? bbuf0 : bbuf1;
        bf16x8 a_next = a_cur;
        if (ks + 1 < 16) {
            stage(ks + 1, bnext);
            const int kk1 = (ks + 1) * 32;
            const unsigned short* hs = (kk1 < DIM) ? hin : agg;
            a_next = *reinterpret_cast<const bf16x8*>(
                hs + (size_t)(m0 + c) * DIM + (kk1 & (DIM - 1)) + q * 8);
        }
        #pragma unroll
        for (int nf = 0; nf < 16; ++nf) {
            bf16x8 bfr = *reinterpret_cast<const bf16x8*>(bb + nf * 512 + lane * 8);
            acc[nf] = __builtin_amdgcn_mfma_f32_16x16x32_bf16(a_cur, bfr, acc[nf], 0, 0, 0);
        }
        __syncthreads();
        a_cur = a_next;
    }

    // LN + ReLU + next-layer score
    #pragma unroll
    for (int r = 0; r < 4; ++r) {
        float s = 0.f, s2 = 0.f;
        #pragma unroll
        for (int nf = 0; nf < 16; ++nf) {
            float v = acc[nf][r];
            s += v; s2 += v * v;
        }
        #pragma unroll
        for (int msk = 1; msk < 16; msk <<= 1) {
            s  += __shfl_xor(s, msk);
            s2 += __shfl_xor(s2, msk);
        }
        float mu = s * (1.f / DIM);
        float var = s2 * (1.f / DIM) - mu * mu;
        float rstd = rsqrtf(var + 1e-5f);
        float sc = 0.f;
        #pragma unroll
        for (int nf = 0; nf < 16; ++nf) {
            float v = fmaxf(gamma_l[nf * 16 + c] * (acc[nf][r] - mu) * rstd + beta_l[nf * 16 + c], 0.f);
            acc[nf][r] = v;
            if (w_src_next) sc += v * w_src_next[nf * 16 + c];
        }
        if (w_src_next) {
            #pragma unroll
            for (int msk = 1; msk < 16; msk <<= 1) sc += __shfl_xor(sc, msk);
            int row = m0 + q * 4 + r;
            if (c == 0 && row < NN) e_src[row] = __expf(sc);
        }
    }

    // pack 16 rows via per-wave LDS staging (aliases B buffers; loop fully barriered)
    unsigned short* myl = (unsigned short*)lds_raw + w * 16 * LDS_STRIDE;
    #pragma unroll
    for (int nf = 0; nf < 16; ++nf) {
        #pragma unroll
        for (int r = 0; r < 4; ++r)
            myl[(q * 4 + r) * LDS_STRIDE + nf * 16 + c] = f2bf(acc[nf][r]);
    }
    #pragma unroll
    for (int i = 0; i < 8; ++i) {
        int row16 = 2 * i + (lane >> 5);
        bf16x8 v = *reinterpret_cast<const bf16x8*>(myl + row16 * LDS_STRIDE + (lane & 31) * 8);
        int grow = m0 + row16;
        if (grow < NN) {
            *reinterpret_cast<bf16x8*>(hout + (size_t)grow * DIM + (lane & 31) * 8) = v;
            if (f8out) {
                uint2 pk;
                pk.x = fp8x4_enc(bf2f((unsigned short)v[0]), bf2f((unsigned short)v[1]),
                                 bf2f((unsigned short)v[2]), bf2f((unsigned short)v[3]));
                pk.y = fp8x4_enc(bf2f((unsigned short)v[4]), bf2f((unsigned short)v[5]),
                                 bf2f((unsigned short)v[6]), bf2f((unsigned short)v[7]));
                *reinterpret_cast<uint2*>(f8out + (size_t)grow * DIM + (lane & 31) * 8) = pk;
            }
        }
    }

    // fused column-sum of this block's 64 output rows (last layer only; rows sit in LDS)
    if (colsum) {
        __syncthreads();
        int t = threadIdx.x;
        float s = 0.f;
        unsigned short* l0 = (unsigned short*)lds_raw;
        #pragma unroll 4
        for (int r = 0; r < 64; ++r) {
            if (blockIdx.x * 64 + r < NN)
                s += bf2f(l0[((r >> 4) * 16 + (r & 15)) * LDS_STRIDE + t]);
        }
        atomicAdd(&colsum[t], s);
    }
}

// ---------------- column sum (fp32 input) ----------------
__global__ __launch_bounds__(256) void k_colsum_f32(const float* __restrict__ mat, float* __restrict__ out) {
    int j = threadIdx.x;
    float s = 0.f;
    for (int r = blockIdx.x; r < NN; r += gridDim.x) s += mat[(size_t)r * DIM + j];
    atomicAdd(&out[j], s);
}

// ---------------- final: out = mean(h) + mean(x) @ W_skip + b_skip ----------------
__global__ __launch_bounds__(256) void k_final(const float* __restrict__ hsum, const float* __restrict__ xsum,
                                               const float* __restrict__ W_skip, const float* __restrict__ b_skip,
                                               float* __restrict__ out) {
    int j = threadIdx.x;
    float acc = 0.f;
    const float invN = 1.f / (float)NN;
    for (int i = 0; i < DIM; ++i) acc += (xsum[i] * invN) * W_skip[(size_t)i * DIM + j];
    out[j] = hsum[j] * invN + acc + b_skip[j];
}

extern "C" void kernel_launch(void* const* d_in, const int* in_sizes, int n_in,
                              void* d_out, int out_size, void* d_ws, size_t ws_size,
                              hipStream_t stream) {
    const float* x      = (const float*)d_in[0];
    const int*   ei     = (const int*)d_in[1];
    const float* W_sage = (const float*)d_in[2];
    const float* b_sage = (const float*)d_in[3];
    const float* gamma  = (const float*)d_in[4];
    const float* beta   = (const float*)d_in[5];
    const float* W_attn = (const float*)d_in[6];
    // d_in[7] = b_attn: cancels in the per-dst softmax — unused.
    const float* W_skip = (const float*)d_in[8];
    const float* b_skip = (const float*)d_in[9];
    float* out = (float*)d_out;

    // ---- workspace layout ----
    const size_t ND = (size_t)NN * DIM;
    unsigned short* hx   = (unsigned short*)d_ws;        // ND bf16
    unsigned short* hA   = hx + ND;                      // ND bf16
    unsigned short* hB   = hA + ND;                      // ND bf16
    unsigned short* agg  = hB + ND;                      // ND bf16
    unsigned short* Bp3  = agg + ND;                     // 3*512*256 bf16 (all layers packed)
    unsigned char*  f8a  = (unsigned char*)(Bp3 + 3 * (size_t)KDIM * DIM + 64);  // ND fp8
    unsigned char*  f8b  = f8a + ND;                     // ND fp8
    float* e_src  = (float*)(f8b + ND + 64);             // NN (pad for OOB A-read slack)
    float* colsum = e_src + NN;                          // DIM
    float* xsum   = colsum + DIM;                        // DIM
    int*   cursor = (int*)(xsum + DIM);                  // NN degree counters
    unsigned short* csr = (unsigned short*)(cursor + NN);  // NN*CAP ushorts (8 MB)

    const int NBLK_RANGED = NRANGE * 784;  // 8 ranges x 784 stride-blocks

    hipError_t err;
    err = hipMemsetAsync(cursor, 0, (size_t)NN * sizeof(int), stream); (void)err;
    err = hipMemsetAsync(colsum, 0, 2 * DIM * sizeof(float), stream); (void)err;

    // CSR build: single scatter pass (fixed-capacity rows; cursor = degree counter)
    k_scatter<<<NBLK_RANGED, 256, 0, stream>>>(ei, cursor, csr);

    // x -> bf16 + fp8 + layer-0 scores; xsum; all-layer B pack
    k_prep<<<NN / 4, 256, 0, stream>>>(x, W_attn + DIM, hx, f8a, e_src);
    k_colsum_f32<<<256, 256, 0, stream>>>(x, xsum);
    k_packB3<<<3 * (KDIM * DIM) / 256, 256, 0, stream>>>(W_sage, Bp3);

    unsigned short* hbufs[4]  = {hx, hA, hB, hA};
    unsigned char*  f8bufs[3] = {f8a, f8b, f8a};   // ping-pong; layer-2 f8 output unused
    for (int l = 0; l < NLAYER; ++l) {
        const bool last = (l == NLAYER - 1);
        k_aggregate<<<NN / 4, 256, 0, stream>>>(f8bufs[l], e_src, cursor, csr, agg);
        const float* wnext = last ? nullptr : (W_attn + (size_t)(l + 1) * KDIM + DIM);
        unsigned char* f8next = last ? nullptr : f8bufs[l + 1];
        k_gemm_ln<<<(NN + 63) / 64, 256, 0, stream>>>(
            hbufs[l], agg, Bp3 + (size_t)l * KDIM * DIM, b_sage + (size_t)l * DIM,
            gamma + (size_t)l * DIM, beta + (size_t)l * DIM,
            wnext, hbufs[l + 1], f8next, e_src,
            last ? colsum : nullptr);
    }

    k_final<<<1, 256, 0, stream>>>(colsum, xsum, W_skip, b_skip, out);
}

// Round 18
// 491.703 us; speedup vs baseline: 1.1438x; 1.0128x over previous
//
#include <hip/hip_runtime.h>
#include <hip/hip_bf16.h>

#define NN 50000
#define EE 1600000
#define DIM 256
#define KDIM 512
#define NLAYER 3
#define NRANGE 4
#define RNODES (NN / NRANGE)   // 12500
#define CAP 80                 // fixed CSR row capacity; P(deg>80) ~ 1e-17 per node

using bf16x8 = __attribute__((ext_vector_type(8))) short;
using f32x4  = __attribute__((ext_vector_type(4))) float;
using f32x2  = __attribute__((ext_vector_type(2))) float;

static __device__ __forceinline__ unsigned short f2bf(float f) {
    unsigned u = __builtin_bit_cast(unsigned, f);
    unsigned r = (u + 0x7FFFu + ((u >> 16) & 1u)) >> 16;   // RNE
    return (unsigned short)r;
}
static __device__ __forceinline__ float bf2f(unsigned short s) {
    return __builtin_bit_cast(float, (unsigned)s << 16);
}

// ---- async global->LDS, 16B per lane. LDS dest is wave-uniform base + lane*16 (G21).
static __device__ __forceinline__ void gload_lds16(const void* g, void* l) {
    __builtin_amdgcn_global_load_lds(
        reinterpret_cast<const __attribute__((address_space(1))) void*>(
            reinterpret_cast<uintptr_t>(g)),
        reinterpret_cast<__attribute__((address_space(3))) void*>(
            static_cast<unsigned>(reinterpret_cast<uintptr_t>(l))),
        16, 0, 0);
}

// ---- fp8 e4m3 (OCP) helpers ----
#if defined(__has_builtin) && __has_builtin(__builtin_amdgcn_cvt_pk_f32_fp8) && __has_builtin(__builtin_amdgcn_cvt_pk_fp8_f32)
#define FP8_NATIVE 1
#else
#define FP8_NATIVE 0
#endif

template <bool HI>
static __device__ __forceinline__ f32x2 fp8x2_dec(unsigned w) {
#if FP8_NATIVE
    return __builtin_amdgcn_cvt_pk_f32_fp8((int)w, HI);
#else
    unsigned v = HI ? (w >> 16) : w;
    unsigned b0 = v & 0xFFu, b1 = (v >> 8) & 0xFFu;
    unsigned u0 = ((b0 & 0x80u) << 24) | ((b0 & 0x7Fu) << 20);
    unsigned u1 = ((b1 & 0x80u) << 24) | ((b1 & 0x7Fu) << 20);
    f32x2 r;
    r[0] = __builtin_bit_cast(float, u0) * 0x1p120f;
    r[1] = __builtin_bit_cast(float, u1) * 0x1p120f;
    return r;
#endif
}

#if !FP8_NATIVE
static __device__ __forceinline__ unsigned fp8_enc1(float f) {
    unsigned u = __builtin_bit_cast(unsigned, f * 0x1p-120f);
    unsigned s = (u >> 24) & 0x80u;
    unsigned m = u & 0x7FFFFFFFu;
    m = m + 0x7FFFFu + ((m >> 20) & 1u);
    return s | ((m >> 20) & 0x7Fu);
}
#endif

static __device__ __forceinline__ unsigned fp8x4_enc(float a, float b, float c, float d) {
#if FP8_NATIVE
    int w = __builtin_amdgcn_cvt_pk_fp8_f32(a, b, 0, false);
    w = __builtin_amdgcn_cvt_pk_fp8_f32(c, d, w, true);
    return (unsigned)w;
#else
    return fp8_enc1(a) | (fp8_enc1(b) << 8) | (fp8_enc1(c) << 16) | (fp8_enc1(d) << 24);
#endif
}

// decode 8 fp8 (uint2) scaled by wg into acc[0..7]
static __device__ __forceinline__ void fp8x8_fma(float* acc, uint2 r, float wg) {
    f32x2 p0 = fp8x2_dec<false>(r.x);
    f32x2 p1 = fp8x2_dec<true>(r.x);
    f32x2 p2 = fp8x2_dec<false>(r.y);
    f32x2 p3 = fp8x2_dec<true>(r.y);
    acc[0] += wg * p0[0]; acc[1] += wg * p0[1];
    acc[2] += wg * p1[0]; acc[3] += wg * p1[1];
    acc[4] += wg * p2[0]; acc[5] += wg * p2[1];
    acc[6] += wg * p3[0]; acc[7] += wg * p3[1];
}

// ---------------- prep: x (fp32) -> h0 (bf16 + fp8), e_src0 = exp(x . w_src0) ----------------
__global__ __launch_bounds__(256) void k_prep(const float* __restrict__ x,
                                              const float* __restrict__ w_src,
                                              unsigned short* __restrict__ hout,
                                              unsigned char* __restrict__ f8out,
                                              float* __restrict__ e_src) {
    int wave = threadIdx.x >> 6, lane = threadIdx.x & 63;
    int n = blockIdx.x * 4 + wave;
    if (n >= NN) return;
    const float4 v = *reinterpret_cast<const float4*>(x + (size_t)n * DIM + lane * 4);
    const float4 wv = *reinterpret_cast<const float4*>(w_src + lane * 4);
    float sc = v.x * wv.x + v.y * wv.y + v.z * wv.z + v.w * wv.w;
    #pragma unroll
    for (int m = 32; m; m >>= 1) sc += __shfl_xor(sc, m);
    if (lane == 0) e_src[n] = __expf(sc);
    ushort4 o;
    o.x = f2bf(v.x); o.y = f2bf(v.y); o.z = f2bf(v.z); o.w = f2bf(v.w);
    *reinterpret_cast<ushort4*>(hout + (size_t)n * DIM + lane * 4) = o;
    *reinterpret_cast<unsigned*>(f8out + (size_t)n * DIM + lane * 4) =
        fp8x4_enc(v.x, v.y, v.z, v.w);
}

// ---------------- CSR build: single range-partitioned scatter into fixed-CAP rows ----------
// NRANGE=4: dst stream re-read 4x (28 MB fetch vs 50 at NRANGE=8); write side atomic-bound.
__global__ __launch_bounds__(256) void k_scatter(const int* __restrict__ ei, int* __restrict__ cursor,
                                                 unsigned short* __restrict__ csr) {
    const int range = blockIdx.x & (NRANGE - 1);
    const int lo = range * RNODES, hi = lo + RNODES;
    const int stride = (gridDim.x >> 2) * 256;
    for (int e = (blockIdx.x >> 2) * 256 + threadIdx.x; e < EE; e += stride) {
        int d = ei[EE + e];
        if (d >= lo && d < hi) {
            int pos = atomicAdd(&cursor[d], 1);
            if (pos < CAP) csr[d * CAP + pos] = (unsigned short)ei[e];
        }
    }
}

// ---------------- attention aggregation over fp8 rows: 8 edges per wave-iteration ----------
// half-wave h takes 4 consecutive edges; each half-wave covers a full 256-col row.
__global__ __launch_bounds__(256) void k_aggregate(const unsigned char* __restrict__ f8,
                                                   const float* __restrict__ e_src,
                                                   const int* __restrict__ cursor,
                                                   const unsigned short* __restrict__ csr,
                                                   unsigned short* __restrict__ agg) {
    int wave = threadIdx.x >> 6, lane = threadIdx.x & 63;
    int n = blockIdx.x * 4 + wave;
    if (n >= NN) return;
    int deg = cursor[n];
    if (deg > CAP) deg = CAP;
    const unsigned short* row = csr + (size_t)n * CAP;
    const int half = lane >> 5;
    const int col8 = (lane & 31) * 8;

    float acc[8] = {0.f, 0.f, 0.f, 0.f, 0.f, 0.f, 0.f, 0.f};
    float den = 0.f;

    int p = 0;
    #pragma unroll 2
    for (; p + 8 <= deg; p += 8) {
        int b = p + 4 * half;
        int s0 = row[b + 0];
        int s1 = row[b + 1];
        int s2 = row[b + 2];
        int s3 = row[b + 3];
        float w0 = e_src[s0], w1 = e_src[s1], w2 = e_src[s2], w3 = e_src[s3];
        uint2 r0 = *reinterpret_cast<const uint2*>(f8 + (size_t)s0 * DIM + col8);
        uint2 r1 = *reinterpret_cast<const uint2*>(f8 + (size_t)s1 * DIM + col8);
        uint2 r2 = *reinterpret_cast<const uint2*>(f8 + (size_t)s2 * DIM + col8);
        uint2 r3 = *reinterpret_cast<const uint2*>(f8 + (size_t)s3 * DIM + col8);
        fp8x8_fma(acc, r0, w0);
        fp8x8_fma(acc, r1, w1);
        fp8x8_fma(acc, r2, w2);
        fp8x8_fma(acc, r3, w3);
        den += (w0 + w1) + (w2 + w3);
    }
    for (; p < deg; p += 2) {
        int idx = p + half;
        bool valid = idx < deg;
        int s0 = row[valid ? idx : 0];
        float w0 = valid ? e_src[s0] : 0.f;
        uint2 r0 = *reinterpret_cast<const uint2*>(f8 + (size_t)s0 * DIM + col8);
        fp8x8_fma(acc, r0, w0);
        den += w0;
    }

    den += __shfl_xor(den, 32);
    float inv = (deg > 0 && den > 0.f) ? 1.f / den : 0.f;
    #pragma unroll
    for (int j = 0; j < 8; ++j) acc[j] += __shfl_xor(acc[j], 32);

    if (half == 0) {
        bf16x8 o;
        #pragma unroll
        for (int j = 0; j < 8; ++j) o[j] = (short)f2bf(acc[j] * inv);
        *reinterpret_cast<bf16x8*>(agg + (size_t)n * DIM + col8) = o;
    }
}

// ---------------- pack all 3 layers' W -> Bp3 bf16, lane-linear MFMA-B fragments ----------
__global__ __launch_bounds__(256) void k_packB3(const float* __restrict__ W_all,
                                                unsigned short* __restrict__ Bp3) {
    int gid = blockIdx.x * 256 + threadIdx.x;
    int l   = gid >> 17;                 // 131072 elements per layer
    int tid = gid & 131071;
    int j    = tid & 7;
    int lane = (tid >> 3) & 63;
    int nf   = (tid >> 9) & 15;
    int ks   = tid >> 13;
    int c = lane & 15, q = lane >> 4;
    Bp3[gid] = f2bf(W_all[(size_t)l * KDIM * DIM + (size_t)(ks * 32 + q * 8 + j) * DIM + nf * 16 + c]);
}

// ---------------- fused MFMA GEMM + LN + ReLU + score + packs (+ colsum on last layer) -----
#define LDS_STRIDE 264
__global__ __launch_bounds__(256) void k_gemm_ln(const unsigned short* __restrict__ hin,
                                                 const unsigned short* __restrict__ agg,
                                                 const unsigned short* __restrict__ Bp,
                                                 const float* __restrict__ bias,
                                                 const float* __restrict__ gamma_l,
                                                 const float* __restrict__ beta_l,
                                                 const float* __restrict__ w_src_next,  // null on last layer
                                                 unsigned short* __restrict__ hout,
                                                 unsigned char* __restrict__ f8out,     // null on last layer
                                                 float* __restrict__ e_src,
                                                 float* __restrict__ colsum) {          // non-null on last layer
    __shared__ __align__(16) unsigned char lds_raw[4 * 16 * LDS_STRIDE * 2];  // 33792 B
    unsigned short* bbuf0 = (unsigned short*)lds_raw;           // 16 KB
    unsigned short* bbuf1 = bbuf0 + 8192;                       // 16 KB
    int w = threadIdx.x >> 6, lane = threadIdx.x & 63;
    int c = lane & 15, q = lane >> 4;
    int m0 = blockIdx.x * 64 + w * 16;

    auto stage = [&](int ks, unsigned short* buf) {
        const unsigned short* g = Bp + (size_t)ks * 8192 + w * 2048 + lane * 8;
        unsigned short* l = buf + w * 2048;   // wave-uniform base
        #pragma unroll
        for (int i = 0; i < 4; ++i)
            gload_lds16(g + i * 512, l + i * 512);
    };

    f32x4 acc[16];
    #pragma unroll
    for (int nf = 0; nf < 16; ++nf) {
        float b = bias[nf * 16 + c];
        acc[nf] = (f32x4){b, b, b, b};
    }

    stage(0, bbuf0);
    bf16x8 a_cur = *reinterpret_cast<const bf16x8*>(hin + (size_t)(m0 + c) * DIM + q * 8);
    __syncthreads();

    #pragma unroll
    for (int ks = 0; ks < 16; ++ks) {
        const unsigned short* bb = (ks & 1) ? bbuf1 : bbuf0;
        unsigned short* bnext    = (ks & 1) ? bbuf0 : bbuf1;
        bf16x8 a_next = a_cur;
        if (ks + 1 < 16) {
            stage(ks + 1, bnext);
            const int kk1 = (ks + 1) * 32;
            const unsigned short* hs = (kk1 < DIM) ? hin : agg;
            a_next = *reinterpret_cast<const bf16x8*>(
                hs + (size_t)(m0 + c) * DIM + (kk1 & (DIM - 1)) + q * 8);
        }
        #pragma unroll
        for (int nf = 0; nf < 16; ++nf) {
            bf16x8 bfr = *reinterpret_cast<const bf16x8*>(bb + nf * 512 + lane * 8);
            acc[nf] = __builtin_amdgcn_mfma_f32_16x16x32_bf16(a_cur, bfr, acc[nf], 0, 0, 0);
        }
        __syncthreads();
        a_cur = a_next;
    }

    // LN + ReLU + next-layer score
    #pragma unroll
    for (int r = 0; r < 4; ++r) {
        float s = 0.f, s2 = 0.f;
        #pragma unroll
        for (int nf = 0; nf < 16; ++nf) {
            float v = acc[nf][r];
            s += v; s2 += v * v;
        }
        #pragma unroll
        for (int msk = 1; msk < 16; msk <<= 1) {
            s  += __shfl_xor(s, msk);
            s2 += __shfl_xor(s2, msk);
        }
        float mu = s * (1.f / DIM);
        float var = s2 * (1.f / DIM) - mu * mu;
        float rstd = rsqrtf(var + 1e-5f);
        float sc = 0.f;
        #pragma unroll
        for (int nf = 0; nf < 16; ++nf) {
            float v = fmaxf(gamma_l[nf * 16 + c] * (acc[nf][r] - mu) * rstd + beta_l[nf * 16 + c], 0.f);
            acc[nf][r] = v;
            if (w_src_next) sc += v * w_src_next[nf * 16 + c];
        }
        if (w_src_next) {
            #pragma unroll
            for (int msk = 1; msk < 16; msk <<= 1) sc += __shfl_xor(sc, msk);
            int row = m0 + q * 4 + r;
            if (c == 0 && row < NN) e_src[row] = __expf(sc);
        }
    }

    // pack 16 rows via per-wave LDS staging (aliases B buffers; loop fully barriered)
    unsigned short* myl = (unsigned short*)lds_raw + w * 16 * LDS_STRIDE;
    #pragma unroll
    for (int nf = 0; nf < 16; ++nf) {
        #pragma unroll
        for (int r = 0; r < 4; ++r)
            myl[(q * 4 + r) * LDS_STRIDE + nf * 16 + c] = f2bf(acc[nf][r]);
    }
    #pragma unroll
    for (int i = 0; i < 8; ++i) {
        int row16 = 2 * i + (lane >> 5);
        bf16x8 v = *reinterpret_cast<const bf16x8*>(myl + row16 * LDS_STRIDE + (lane & 31) * 8);
        int grow = m0 + row16;
        if (grow < NN) {
            *reinterpret_cast<bf16x8*>(hout + (size_t)grow * DIM + (lane & 31) * 8) = v;
            if (f8out) {
                uint2 pk;
                pk.x = fp8x4_enc(bf2f((unsigned short)v[0]), bf2f((unsigned short)v[1]),
                                 bf2f((unsigned short)v[2]), bf2f((unsigned short)v[3]));
                pk.y = fp8x4_enc(bf2f((unsigned short)v[4]), bf2f((unsigned short)v[5]),
                                 bf2f((unsigned short)v[6]), bf2f((unsigned short)v[7]));
                *reinterpret_cast<uint2*>(f8out + (size_t)grow * DIM + (lane & 31) * 8) = pk;
            }
        }
    }

    // fused column-sum of this block's 64 output rows (last layer only; rows sit in LDS)
    if (colsum) {
        __syncthreads();
        int t = threadIdx.x;
        float s = 0.f;
        unsigned short* l0 = (unsigned short*)lds_raw;
        #pragma unroll 4
        for (int r = 0; r < 64; ++r) {
            if (blockIdx.x * 64 + r < NN)
                s += bf2f(l0[((r >> 4) * 16 + (r & 15)) * LDS_STRIDE + t]);
        }
        atomicAdd(&colsum[t], s);
    }
}

// ---------------- column sum (fp32 input) ----------------
__global__ __launch_bounds__(256) void k_colsum_f32(const float* __restrict__ mat, float* __restrict__ out) {
    int j = threadIdx.x;
    float s = 0.f;
    for (int r = blockIdx.x; r < NN; r += gridDim.x) s += mat[(size_t)r * DIM + j];
    atomicAdd(&out[j], s);
}

// ---------------- final: out = mean(h) + mean(x) @ W_skip + b_skip ----------------
__global__ __launch_bounds__(256) void k_final(const float* __restrict__ hsum, const float* __restrict__ xsum,
                                               const float* __restrict__ W_skip, const float* __restrict__ b_skip,
                                               float* __restrict__ out) {
    int j = threadIdx.x;
    float acc = 0.f;
    const float invN = 1.f / (float)NN;
    for (int i = 0; i < DIM; ++i) acc += (xsum[i] * invN) * W_skip[(size_t)i * DIM + j];
    out[j] = hsum[j] * invN + acc + b_skip[j];
}

extern "C" void kernel_launch(void* const* d_in, const int* in_sizes, int n_in,
                              void* d_out, int out_size, void* d_ws, size_t ws_size,
                              hipStream_t stream) {
    const float* x      = (const float*)d_in[0];
    const int*   ei     = (const int*)d_in[1];
    const float* W_sage = (const float*)d_in[2];
    const float* b_sage = (const float*)d_in[3];
    const float* gamma  = (const float*)d_in[4];
    const float* beta   = (const float*)d_in[5];
    const float* W_attn = (const float*)d_in[6];
    // d_in[7] = b_attn: cancels in the per-dst softmax — unused.
    const float* W_skip = (const float*)d_in[8];
    const float* b_skip = (const float*)d_in[9];
    float* out = (float*)d_out;

    // ---- workspace layout ----
    const size_t ND = (size_t)NN * DIM;
    unsigned short* hx   = (unsigned short*)d_ws;        // ND bf16
    unsigned short* hA   = hx + ND;                      // ND bf16
    unsigned short* hB   = hA + ND;                      // ND bf16
    unsigned short* agg  = hB + ND;                      // ND bf16
    unsigned short* Bp3  = agg + ND;                     // 3*512*256 bf16 (all layers packed)
    unsigned char*  f8a  = (unsigned char*)(Bp3 + 3 * (size_t)KDIM * DIM + 64);  // ND fp8
    unsigned char*  f8b  = f8a + ND;                     // ND fp8
    float* e_src  = (float*)(f8b + ND + 64);             // NN (pad for OOB A-read slack)
    float* colsum = e_src + NN;                          // DIM
    float* xsum   = colsum + DIM;                        // DIM
    int*   cursor = (int*)(xsum + DIM);                  // NN degree counters
    unsigned short* csr = (unsigned short*)(cursor + NN);  // NN*CAP ushorts (8 MB)

    const int NBLK_RANGED = NRANGE * 1568;  // 4 ranges x 1568 stride-blocks

    hipError_t err;
    err = hipMemsetAsync(cursor, 0, (size_t)NN * sizeof(int), stream); (void)err;
    err = hipMemsetAsync(colsum, 0, 2 * DIM * sizeof(float), stream); (void)err;

    // CSR build: single scatter pass (fixed-capacity rows; cursor = degree counter)
    k_scatter<<<NBLK_RANGED, 256, 0, stream>>>(ei, cursor, csr);

    // x -> bf16 + fp8 + layer-0 scores; xsum; all-layer B pack
    k_prep<<<NN / 4, 256, 0, stream>>>(x, W_attn + DIM, hx, f8a, e_src);
    k_colsum_f32<<<256, 256, 0, stream>>>(x, xsum);
    k_packB3<<<3 * (KDIM * DIM) / 256, 256, 0, stream>>>(W_sage, Bp3);

    unsigned short* hbufs[4]  = {hx, hA, hB, hA};
    unsigned char*  f8bufs[3] = {f8a, f8b, f8a};   // ping-pong; layer-2 f8 output unused
    for (int l = 0; l < NLAYER; ++l) {
        const bool last = (l == NLAYER - 1);
        k_aggregate<<<NN / 4, 256, 0, stream>>>(f8bufs[l], e_src, cursor, csr, agg);
        const float* wnext = last ? nullptr : (W_attn + (size_t)(l + 1) * KDIM + DIM);
        unsigned char* f8next = last ? nullptr : f8bufs[l + 1];
        k_gemm_ln<<<(NN + 63) / 64, 256, 0, stream>>>(
            hbufs[l], agg, Bp3 + (size_t)l * KDIM * DIM, b_sage + (size_t)l * DIM,
            gamma + (size_t)l * DIM, beta + (size_t)l * DIM,
            wnext, hbufs[l + 1], f8next, e_src,
            last ? colsum : nullptr);
    }

    k_final<<<1, 256, 0, stream>>>(colsum, xsum, W_skip, b_skip, out);
}

// Round 19
// 477.373 us; speedup vs baseline: 1.1781x; 1.0300x over previous
//
#include <hip/hip_runtime.h>
#include <hip/hip_bf16.h>

#define NN 50000
#define EE 1600000
#define DIM 256
#define KDIM 512
#define NLAYER 3
#define NRANGE 4
#define RNODES (NN / NRANGE)   // 12500
#define CAP 80                 // fixed CSR row capacity; P(deg>80) ~ 1e-17 per node

// setup-kernel grid partition
#define NBLK_SC   (NRANGE * 1568)          // 6272 scatter blocks (long pole -> first)
#define NBLK_PREP ((NN + 3) / 4)           // 12500
#define NBLK_CS   256
#define NBLK_PB   (3 * KDIM * DIM / 256)   // 1536
#define NBLK_SETUP (NBLK_SC + NBLK_PREP + NBLK_CS + NBLK_PB)

using bf16x8 = __attribute__((ext_vector_type(8))) short;
using f32x4  = __attribute__((ext_vector_type(4))) float;
using f32x2  = __attribute__((ext_vector_type(2))) float;

static __device__ __forceinline__ unsigned short f2bf(float f) {
    unsigned u = __builtin_bit_cast(unsigned, f);
    unsigned r = (u + 0x7FFFu + ((u >> 16) & 1u)) >> 16;   // RNE
    return (unsigned short)r;
}
static __device__ __forceinline__ float bf2f(unsigned short s) {
    return __builtin_bit_cast(float, (unsigned)s << 16);
}

// ---- async global->LDS, 16B per lane. LDS dest is wave-uniform base + lane*16 (G21).
static __device__ __forceinline__ void gload_lds16(const void* g, void* l) {
    __builtin_amdgcn_global_load_lds(
        reinterpret_cast<const __attribute__((address_space(1))) void*>(
            reinterpret_cast<uintptr_t>(g)),
        reinterpret_cast<__attribute__((address_space(3))) void*>(
            static_cast<unsigned>(reinterpret_cast<uintptr_t>(l))),
        16, 0, 0);
}

// ---- fp8 e4m3 (OCP) helpers ----
#if defined(__has_builtin) && __has_builtin(__builtin_amdgcn_cvt_pk_f32_fp8) && __has_builtin(__builtin_amdgcn_cvt_pk_fp8_f32)
#define FP8_NATIVE 1
#else
#define FP8_NATIVE 0
#endif

template <bool HI>
static __device__ __forceinline__ f32x2 fp8x2_dec(unsigned w) {
#if FP8_NATIVE
    return __builtin_amdgcn_cvt_pk_f32_fp8((int)w, HI);
#else
    unsigned v = HI ? (w >> 16) : w;
    unsigned b0 = v & 0xFFu, b1 = (v >> 8) & 0xFFu;
    unsigned u0 = ((b0 & 0x80u) << 24) | ((b0 & 0x7Fu) << 20);
    unsigned u1 = ((b1 & 0x80u) << 24) | ((b1 & 0x7Fu) << 20);
    f32x2 r;
    r[0] = __builtin_bit_cast(float, u0) * 0x1p120f;
    r[1] = __builtin_bit_cast(float, u1) * 0x1p120f;
    return r;
#endif
}

#if !FP8_NATIVE
static __device__ __forceinline__ unsigned fp8_enc1(float f) {
    unsigned u = __builtin_bit_cast(unsigned, f * 0x1p-120f);
    unsigned s = (u >> 24) & 0x80u;
    unsigned m = u & 0x7FFFFFFFu;
    m = m + 0x7FFFFu + ((m >> 20) & 1u);
    return s | ((m >> 20) & 0x7Fu);
}
#endif

static __device__ __forceinline__ unsigned fp8x4_enc(float a, float b, float c, float d) {
#if FP8_NATIVE
    int w = __builtin_amdgcn_cvt_pk_fp8_f32(a, b, 0, false);
    w = __builtin_amdgcn_cvt_pk_fp8_f32(c, d, w, true);
    return (unsigned)w;
#else
    return fp8_enc1(a) | (fp8_enc1(b) << 8) | (fp8_enc1(c) << 16) | (fp8_enc1(d) << 24);
#endif
}

// decode 8 fp8 (uint2) scaled by wg into acc[0..7]
static __device__ __forceinline__ void fp8x8_fma(float* acc, uint2 r, float wg) {
    f32x2 p0 = fp8x2_dec<false>(r.x);
    f32x2 p1 = fp8x2_dec<true>(r.x);
    f32x2 p2 = fp8x2_dec<false>(r.y);
    f32x2 p3 = fp8x2_dec<true>(r.y);
    acc[0] += wg * p0[0]; acc[1] += wg * p0[1];
    acc[2] += wg * p1[0]; acc[3] += wg * p1[1];
    acc[4] += wg * p2[0]; acc[5] += wg * p2[1];
    acc[6] += wg * p3[0]; acc[7] += wg * p3[1];
}

// ---------------- MERGED setup: scatter | prep | xsum | packB3 (independent block ranges) ---
// scatter blocks first: they form the long pole; the other paths backfill CUs as they drain.
__global__ __launch_bounds__(256) void k_setup(const int* __restrict__ ei,
                                               int* __restrict__ cursor,
                                               unsigned short* __restrict__ csr,
                                               const float* __restrict__ x,
                                               const float* __restrict__ w_src0,
                                               unsigned short* __restrict__ hout,
                                               unsigned char* __restrict__ f8out,
                                               float* __restrict__ e_src,
                                               float* __restrict__ xsum,
                                               const float* __restrict__ W_all,
                                               unsigned short* __restrict__ Bp3) {
    int bid = blockIdx.x;

    if (bid < NBLK_SC) {
        // ---- scatter path ----
        const int range = bid & (NRANGE - 1);
        const int lo = range * RNODES, hi = lo + RNODES;
        const int stride = (NBLK_SC >> 2) * 256;
        for (int e = (bid >> 2) * 256 + threadIdx.x; e < EE; e += stride) {
            int d = ei[EE + e];
            if (d >= lo && d < hi) {
                int pos = atomicAdd(&cursor[d], 1);
                if (pos < CAP) csr[d * CAP + pos] = (unsigned short)ei[e];
            }
        }
        return;
    }
    bid -= NBLK_SC;

    if (bid < NBLK_PREP) {
        // ---- prep path: x -> bf16 + fp8 + layer-0 scores ----
        int wave = threadIdx.x >> 6, lane = threadIdx.x & 63;
        int n = bid * 4 + wave;
        if (n >= NN) return;
        const float4 v = *reinterpret_cast<const float4*>(x + (size_t)n * DIM + lane * 4);
        const float4 wv = *reinterpret_cast<const float4*>(w_src0 + lane * 4);
        float sc = v.x * wv.x + v.y * wv.y + v.z * wv.z + v.w * wv.w;
        #pragma unroll
        for (int m = 32; m; m >>= 1) sc += __shfl_xor(sc, m);
        if (lane == 0) e_src[n] = __expf(sc);
        ushort4 o;
        o.x = f2bf(v.x); o.y = f2bf(v.y); o.z = f2bf(v.z); o.w = f2bf(v.w);
        *reinterpret_cast<ushort4*>(hout + (size_t)n * DIM + lane * 4) = o;
        *reinterpret_cast<unsigned*>(f8out + (size_t)n * DIM + lane * 4) =
            fp8x4_enc(v.x, v.y, v.z, v.w);
        return;
    }
    bid -= NBLK_PREP;

    if (bid < NBLK_CS) {
        // ---- xsum path (column sums of x) ----
        int j = threadIdx.x;
        float s = 0.f;
        for (int r = bid; r < NN; r += NBLK_CS) s += x[(size_t)r * DIM + j];
        atomicAdd(&xsum[j], s);
        return;
    }
    bid -= NBLK_CS;

    // ---- packB3 path: all 3 layers' W -> lane-linear MFMA-B fragments ----
    {
        int gid = bid * 256 + threadIdx.x;
        int l   = gid >> 17;                 // 131072 elements per layer
        int tid = gid & 131071;
        int j    = tid & 7;
        int lane = (tid >> 3) & 63;
        int nf   = (tid >> 9) & 15;
        int ks   = tid >> 13;
        int c = lane & 15, q = lane >> 4;
        Bp3[gid] = f2bf(W_all[(size_t)l * KDIM * DIM + (size_t)(ks * 32 + q * 8 + j) * DIM + nf * 16 + c]);
    }
}

// ---------------- attention aggregation over fp8 rows: 8 edges per wave-iteration ----------
// half-wave h takes 4 consecutive edges; each half-wave covers a full 256-col row.
__global__ __launch_bounds__(256) void k_aggregate(const unsigned char* __restrict__ f8,
                                                   const float* __restrict__ e_src,
                                                   const int* __restrict__ cursor,
                                                   const unsigned short* __restrict__ csr,
                                                   unsigned short* __restrict__ agg) {
    int wave = threadIdx.x >> 6, lane = threadIdx.x & 63;
    int n = blockIdx.x * 4 + wave;
    if (n >= NN) return;
    int deg = cursor[n];
    if (deg > CAP) deg = CAP;
    const unsigned short* row = csr + (size_t)n * CAP;
    const int half = lane >> 5;
    const int col8 = (lane & 31) * 8;

    float acc[8] = {0.f, 0.f, 0.f, 0.f, 0.f, 0.f, 0.f, 0.f};
    float den = 0.f;

    int p = 0;
    #pragma unroll 2
    for (; p + 8 <= deg; p += 8) {
        int b = p + 4 * half;
        int s0 = row[b + 0];
        int s1 = row[b + 1];
        int s2 = row[b + 2];
        int s3 = row[b + 3];
        float w0 = e_src[s0], w1 = e_src[s1], w2 = e_src[s2], w3 = e_src[s3];
        uint2 r0 = *reinterpret_cast<const uint2*>(f8 + (size_t)s0 * DIM + col8);
        uint2 r1 = *reinterpret_cast<const uint2*>(f8 + (size_t)s1 * DIM + col8);
        uint2 r2 = *reinterpret_cast<const uint2*>(f8 + (size_t)s2 * DIM + col8);
        uint2 r3 = *reinterpret_cast<const uint2*>(f8 + (size_t)s3 * DIM + col8);
        fp8x8_fma(acc, r0, w0);
        fp8x8_fma(acc, r1, w1);
        fp8x8_fma(acc, r2, w2);
        fp8x8_fma(acc, r3, w3);
        den += (w0 + w1) + (w2 + w3);
    }
    for (; p < deg; p += 2) {
        int idx = p + half;
        bool valid = idx < deg;
        int s0 = row[valid ? idx : 0];
        float w0 = valid ? e_src[s0] : 0.f;
        uint2 r0 = *reinterpret_cast<const uint2*>(f8 + (size_t)s0 * DIM + col8);
        fp8x8_fma(acc, r0, w0);
        den += w0;
    }

    den += __shfl_xor(den, 32);
    float inv = (deg > 0 && den > 0.f) ? 1.f / den : 0.f;
    #pragma unroll
    for (int j = 0; j < 8; ++j) acc[j] += __shfl_xor(acc[j], 32);

    if (half == 0) {
        bf16x8 o;
        #pragma unroll
        for (int j = 0; j < 8; ++j) o[j] = (short)f2bf(acc[j] * inv);
        *reinterpret_cast<bf16x8*>(agg + (size_t)n * DIM + col8) = o;
    }
}

// ---------------- fused MFMA GEMM + LN + ReLU + score + packs (+ colsum on last layer) -----
#define LDS_STRIDE 264
__global__ __launch_bounds__(256) void k_gemm_ln(const unsigned short* __restrict__ hin,
                                                 const unsigned short* __restrict__ agg,
                                                 const unsigned short* __restrict__ Bp,
                                                 const float* __restrict__ bias,
                                                 const float* __restrict__ gamma_l,
                                                 const float* __restrict__ beta_l,
                                                 const float* __restrict__ w_src_next,  // null on last layer
                                                 unsigned short* __restrict__ hout,
                                                 unsigned char* __restrict__ f8out,     // null on last layer
                                                 float* __restrict__ e_src,
                                                 float* __restrict__ colsum) {          // non-null on last layer
    __shared__ __align__(16) unsigned char lds_raw[4 * 16 * LDS_STRIDE * 2];  // 33792 B
    unsigned short* bbuf0 = (unsigned short*)lds_raw;           // 16 KB
    unsigned short* bbuf1 = bbuf0 + 8192;                       // 16 KB
    int w = threadIdx.x >> 6, lane = threadIdx.x & 63;
    int c = lane & 15, q = lane >> 4;
    int m0 = blockIdx.x * 64 + w * 16;

    auto stage = [&](int ks, unsigned short* buf) {
        const unsigned short* g = Bp + (size_t)ks * 8192 + w * 2048 + lane * 8;
        unsigned short* l = buf + w * 2048;   // wave-uniform base
        #pragma unroll
        for (int i = 0; i < 4; ++i)
            gload_lds16(g + i * 512, l + i * 512);
    };

    f32x4 acc[16];
    #pragma unroll
    for (int nf = 0; nf < 16; ++nf) {
        float b = bias[nf * 16 + c];
        acc[nf] = (f32x4){b, b, b, b};
    }

    stage(0, bbuf0);
    bf16x8 a_cur = *reinterpret_cast<const bf16x8*>(hin + (size_t)(m0 + c) * DIM + q * 8);
    __syncthreads();

    #pragma unroll
    for (int ks = 0; ks < 16; ++ks) {
        const unsigned short* bb = (ks & 1) ? bbuf1 : bbuf0;
        unsigned short* bnext    = (ks & 1) ? bbuf0 : bbuf1;
        bf16x8 a_next = a_cur;
        if (ks + 1 < 16) {
            stage(ks + 1, bnext);
            const int kk1 = (ks + 1) * 32;
            const unsigned short* hs = (kk1 < DIM) ? hin : agg;
            a_next = *reinterpret_cast<const bf16x8*>(
                hs + (size_t)(m0 + c) * DIM + (kk1 & (DIM - 1)) + q * 8);
        }
        #pragma unroll
        for (int nf = 0; nf < 16; ++nf) {
            bf16x8 bfr = *reinterpret_cast<const bf16x8*>(bb + nf * 512 + lane * 8);
            acc[nf] = __builtin_amdgcn_mfma_f32_16x16x32_bf16(a_cur, bfr, acc[nf], 0, 0, 0);
        }
        __syncthreads();
        a_cur = a_next;
    }

    // LN + ReLU + next-layer score
    #pragma unroll
    for (int r = 0; r < 4; ++r) {
        float s = 0.f, s2 = 0.f;
        #pragma unroll
        for (int nf = 0; nf < 16; ++nf) {
            float v = acc[nf][r];
            s += v; s2 += v * v;
        }
        #pragma unroll
        for (int msk = 1; msk < 16; msk <<= 1) {
            s  += __shfl_xor(s, msk);
            s2 += __shfl_xor(s2, msk);
        }
        float mu = s * (1.f / DIM);
        float var = s2 * (1.f / DIM) - mu * mu;
        float rstd = rsqrtf(var + 1e-5f);
        float sc = 0.f;
        #pragma unroll
        for (int nf = 0; nf < 16; ++nf) {
            float v = fmaxf(gamma_l[nf * 16 + c] * (acc[nf][r] - mu) * rstd + beta_l[nf * 16 + c], 0.f);
            acc[nf][r] = v;
            if (w_src_next) sc += v * w_src_next[nf * 16 + c];
        }
        if (w_src_next) {
            #pragma unroll
            for (int msk = 1; msk < 16; msk <<= 1) sc += __shfl_xor(sc, msk);
            int row = m0 + q * 4 + r;
            if (c == 0 && row < NN) e_src[row] = __expf(sc);
        }
    }

    // pack 16 rows via per-wave LDS staging (aliases B buffers; loop fully barriered)
    unsigned short* myl = (unsigned short*)lds_raw + w * 16 * LDS_STRIDE;
    #pragma unroll
    for (int nf = 0; nf < 16; ++nf) {
        #pragma unroll
        for (int r = 0; r < 4; ++r)
            myl[(q * 4 + r) * LDS_STRIDE + nf * 16 + c] = f2bf(acc[nf][r]);
    }
    #pragma unroll
    for (int i = 0; i < 8; ++i) {
        int row16 = 2 * i + (lane >> 5);
        bf16x8 v = *reinterpret_cast<const bf16x8*>(myl + row16 * LDS_STRIDE + (lane & 31) * 8);
        int grow = m0 + row16;
        if (grow < NN) {
            *reinterpret_cast<bf16x8*>(hout + (size_t)grow * DIM + (lane & 31) * 8) = v;
            if (f8out) {
                uint2 pk;
                pk.x = fp8x4_enc(bf2f((unsigned short)v[0]), bf2f((unsigned short)v[1]),
                                 bf2f((unsigned short)v[2]), bf2f((unsigned short)v[3]));
                pk.y = fp8x4_enc(bf2f((unsigned short)v[4]), bf2f((unsigned short)v[5]),
                                 bf2f((unsigned short)v[6]), bf2f((unsigned short)v[7]));
                *reinterpret_cast<uint2*>(f8out + (size_t)grow * DIM + (lane & 31) * 8) = pk;
            }
        }
    }

    // fused column-sum of this block's 64 output rows (last layer only; rows sit in LDS)
    if (colsum) {
        __syncthreads();
        int t = threadIdx.x;
        float s = 0.f;
        unsigned short* l0 = (unsigned short*)lds_raw;
        #pragma unroll 4
        for (int r = 0; r < 64; ++r) {
            if (blockIdx.x * 64 + r < NN)
                s += bf2f(l0[((r >> 4) * 16 + (r & 15)) * LDS_STRIDE + t]);
        }
        atomicAdd(&colsum[t], s);
    }
}

// ---------------- final: out = mean(h) + mean(x) @ W_skip + b_skip ----------------
__global__ __launch_bounds__(256) void k_final(const float* __restrict__ hsum, const float* __restrict__ xsum,
                                               const float* __restrict__ W_skip, const float* __restrict__ b_skip,
                                               float* __restrict__ out) {
    int j = threadIdx.x;
    float acc = 0.f;
    const float invN = 1.f / (float)NN;
    for (int i = 0; i < DIM; ++i) acc += (xsum[i] * invN) * W_skip[(size_t)i * DIM + j];
    out[j] = hsum[j] * invN + acc + b_skip[j];
}

extern "C" void kernel_launch(void* const* d_in, const int* in_sizes, int n_in,
                              void* d_out, int out_size, void* d_ws, size_t ws_size,
                              hipStream_t stream) {
    const float* x      = (const float*)d_in[0];
    const int*   ei     = (const int*)d_in[1];
    const float* W_sage = (const float*)d_in[2];
    const float* b_sage = (const float*)d_in[3];
    const float* gamma  = (const float*)d_in[4];
    const float* beta   = (const float*)d_in[5];
    const float* W_attn = (const float*)d_in[6];
    // d_in[7] = b_attn: cancels in the per-dst softmax — unused.
    const float* W_skip = (const float*)d_in[8];
    const float* b_skip = (const float*)d_in[9];
    float* out = (float*)d_out;

    // ---- workspace layout ----
    const size_t ND = (size_t)NN * DIM;
    unsigned short* hx   = (unsigned short*)d_ws;        // ND bf16
    unsigned short* hA   = hx + ND;                      // ND bf16
    unsigned short* hB   = hA + ND;                      // ND bf16
    unsigned short* agg  = hB + ND;                      // ND bf16
    unsigned short* Bp3  = agg + ND;                     // 3*512*256 bf16 (all layers packed)
    unsigned char*  f8a  = (unsigned char*)(Bp3 + 3 * (size_t)KDIM * DIM + 64);  // ND fp8
    unsigned char*  f8b  = f8a + ND;                     // ND fp8
    float* e_src  = (float*)(f8b + ND + 64);             // NN (pad for OOB A-read slack)
    float* colsum = e_src + NN;                          // DIM
    float* xsum   = colsum + DIM;                        // DIM
    int*   cursor = (int*)(xsum + DIM);                  // NN degree counters
    unsigned short* csr = (unsigned short*)(cursor + NN);  // NN*CAP ushorts (8 MB)

    hipError_t err;
    err = hipMemsetAsync(cursor, 0, (size_t)NN * sizeof(int), stream); (void)err;
    err = hipMemsetAsync(colsum, 0, 2 * DIM * sizeof(float), stream); (void)err;

    // merged setup: scatter | prep | xsum | packB3 (independent; scatter blocks lead)
    k_setup<<<NBLK_SETUP, 256, 0, stream>>>(ei, cursor, csr,
                                            x, W_attn + DIM, hx, f8a, e_src, xsum,
                                            W_sage, Bp3);

    unsigned short* hbufs[4]  = {hx, hA, hB, hA};
    unsigned char*  f8bufs[3] = {f8a, f8b, f8a};   // ping-pong; layer-2 f8 output unused
    for (int l = 0; l < NLAYER; ++l) {
        const bool last = (l == NLAYER - 1);
        k_aggregate<<<(NN + 3) / 4, 256, 0, stream>>>(f8bufs[l], e_src, cursor, csr, agg);
        const float* wnext = last ? nullptr : (W_attn + (size_t)(l + 1) * KDIM + DIM);
        unsigned char* f8next = last ? nullptr : f8bufs[l + 1];
        k_gemm_ln<<<(NN + 63) / 64, 256, 0, stream>>>(
            hbufs[l], agg, Bp3 + (size_t)l * KDIM * DIM, b_sage + (size_t)l * DIM,
            gamma + (size_t)l * DIM, beta + (size_t)l * DIM,
            wnext, hbufs[l + 1], f8next, e_src,
            last ? colsum : nullptr);
    }

    k_final<<<1, 256, 0, stream>>>(colsum, xsum, W_skip, b_skip, out);
}

// Round 20
// 454.139 us; speedup vs baseline: 1.2384x; 1.0512x over previous
//
#include <hip/hip_runtime.h>
#include <hip/hip_bf16.h>

#define NN 50000
#define EE 1600000
#define DIM 256
#define KDIM 512
#define NLAYER 3
#define NRANGE 4
#define RNODES (NN / NRANGE)   // 12500
#define CAP 80                 // fixed CSR row capacity; P(deg>80) ~ 1e-17 per node

// setup-kernel grid partition: BW-bound paths first, atomic-bound scatter last
#define NBLK_PREP ((NN + 3) / 4)           // 12500
#define NBLK_CS   1024
#define NBLK_PB   (3 * KDIM * DIM / 256)   // 1536
#define NBLK_SC   (NRANGE * 1568)          // 6272 scatter blocks
#define NBLK_SETUP (NBLK_PREP + NBLK_CS + NBLK_PB + NBLK_SC)

using bf16x8 = __attribute__((ext_vector_type(8))) short;
using f32x4  = __attribute__((ext_vector_type(4))) float;
using f32x2  = __attribute__((ext_vector_type(2))) float;

static __device__ __forceinline__ unsigned short f2bf(float f) {
    unsigned u = __builtin_bit_cast(unsigned, f);
    unsigned r = (u + 0x7FFFu + ((u >> 16) & 1u)) >> 16;   // RNE
    return (unsigned short)r;
}
static __device__ __forceinline__ float bf2f(unsigned short s) {
    return __builtin_bit_cast(float, (unsigned)s << 16);
}

// ---- async global->LDS, 16B per lane. LDS dest is wave-uniform base + lane*16 (G21).
static __device__ __forceinline__ void gload_lds16(const void* g, void* l) {
    __builtin_amdgcn_global_load_lds(
        reinterpret_cast<const __attribute__((address_space(1))) void*>(
            reinterpret_cast<uintptr_t>(g)),
        reinterpret_cast<__attribute__((address_space(3))) void*>(
            static_cast<unsigned>(reinterpret_cast<uintptr_t>(l))),
        16, 0, 0);
}

// ---- fp8 e4m3 (OCP) helpers ----
#if defined(__has_builtin) && __has_builtin(__builtin_amdgcn_cvt_pk_f32_fp8) && __has_builtin(__builtin_amdgcn_cvt_pk_fp8_f32)
#define FP8_NATIVE 1
#else
#define FP8_NATIVE 0
#endif

template <bool HI>
static __device__ __forceinline__ f32x2 fp8x2_dec(unsigned w) {
#if FP8_NATIVE
    return __builtin_amdgcn_cvt_pk_f32_fp8((int)w, HI);
#else
    unsigned v = HI ? (w >> 16) : w;
    unsigned b0 = v & 0xFFu, b1 = (v >> 8) & 0xFFu;
    unsigned u0 = ((b0 & 0x80u) << 24) | ((b0 & 0x7Fu) << 20);
    unsigned u1 = ((b1 & 0x80u) << 24) | ((b1 & 0x7Fu) << 20);
    f32x2 r;
    r[0] = __builtin_bit_cast(float, u0) * 0x1p120f;
    r[1] = __builtin_bit_cast(float, u1) * 0x1p120f;
    return r;
#endif
}

#if !FP8_NATIVE
static __device__ __forceinline__ unsigned fp8_enc1(float f) {
    unsigned u = __builtin_bit_cast(unsigned, f * 0x1p-120f);
    unsigned s = (u >> 24) & 0x80u;
    unsigned m = u & 0x7FFFFFFFu;
    m = m + 0x7FFFFu + ((m >> 20) & 1u);
    return s | ((m >> 20) & 0x7Fu);
}
#endif

static __device__ __forceinline__ unsigned fp8x4_enc(float a, float b, float c, float d) {
#if FP8_NATIVE
    int w = __builtin_amdgcn_cvt_pk_fp8_f32(a, b, 0, false);
    w = __builtin_amdgcn_cvt_pk_fp8_f32(c, d, w, true);
    return (unsigned)w;
#else
    return fp8_enc1(a) | (fp8_enc1(b) << 8) | (fp8_enc1(c) << 16) | (fp8_enc1(d) << 24);
#endif
}

// decode 8 fp8 (uint2) scaled by wg into acc[0..7]
static __device__ __forceinline__ void fp8x8_fma(float* acc, uint2 r, float wg) {
    f32x2 p0 = fp8x2_dec<false>(r.x);
    f32x2 p1 = fp8x2_dec<true>(r.x);
    f32x2 p2 = fp8x2_dec<false>(r.y);
    f32x2 p3 = fp8x2_dec<true>(r.y);
    acc[0] += wg * p0[0]; acc[1] += wg * p0[1];
    acc[2] += wg * p1[0]; acc[3] += wg * p1[1];
    acc[4] += wg * p2[0]; acc[5] += wg * p2[1];
    acc[6] += wg * p3[0]; acc[7] += wg * p3[1];
}

// ---------------- MERGED setup: prep | xsum | packB3 | scatter (independent block ranges) ---
// BW-bound paths first (finish in ~25 us at full width); atomic-bound scatter backfills and
// then runs nearly uncontended.
__global__ __launch_bounds__(256) void k_setup(const int* __restrict__ ei,
                                               int* __restrict__ cursor,
                                               unsigned short* __restrict__ csr,
                                               const float* __restrict__ x,
                                               const float* __restrict__ w_src0,
                                               unsigned short* __restrict__ hout,
                                               unsigned char* __restrict__ f8out,
                                               float* __restrict__ e_src,
                                               float* __restrict__ xsum,
                                               const float* __restrict__ W_all,
                                               unsigned short* __restrict__ Bp3) {
    int bid = blockIdx.x;

    if (bid < NBLK_PREP) {
        // ---- prep path: x -> bf16 + fp8 + layer-0 scores ----
        int wave = threadIdx.x >> 6, lane = threadIdx.x & 63;
        int n = bid * 4 + wave;
        if (n >= NN) return;
        const float4 v = *reinterpret_cast<const float4*>(x + (size_t)n * DIM + lane * 4);
        const float4 wv = *reinterpret_cast<const float4*>(w_src0 + lane * 4);
        float sc = v.x * wv.x + v.y * wv.y + v.z * wv.z + v.w * wv.w;
        #pragma unroll
        for (int m = 32; m; m >>= 1) sc += __shfl_xor(sc, m);
        if (lane == 0) e_src[n] = __expf(sc);
        ushort4 o;
        o.x = f2bf(v.x); o.y = f2bf(v.y); o.z = f2bf(v.z); o.w = f2bf(v.w);
        *reinterpret_cast<ushort4*>(hout + (size_t)n * DIM + lane * 4) = o;
        *reinterpret_cast<unsigned*>(f8out + (size_t)n * DIM + lane * 4) =
            fp8x4_enc(v.x, v.y, v.z, v.w);
        return;
    }
    bid -= NBLK_PREP;

    if (bid < NBLK_CS) {
        // ---- xsum path (column sums of x) ----
        int j = threadIdx.x;
        float s = 0.f;
        for (int r = bid; r < NN; r += NBLK_CS) s += x[(size_t)r * DIM + j];
        atomicAdd(&xsum[j], s);
        return;
    }
    bid -= NBLK_CS;

    if (bid < NBLK_PB) {
        // ---- packB3 path: all 3 layers' W -> lane-linear MFMA-B fragments ----
        int gid = bid * 256 + threadIdx.x;
        int l   = gid >> 17;                 // 131072 elements per layer
        int tid = gid & 131071;
        int j    = tid & 7;
        int lane = (tid >> 3) & 63;
        int nf   = (tid >> 9) & 15;
        int ks   = tid >> 13;
        int c = lane & 15, q = lane >> 4;
        Bp3[gid] = f2bf(W_all[(size_t)l * KDIM * DIM + (size_t)(ks * 32 + q * 8 + j) * DIM + nf * 16 + c]);
        return;
    }
    bid -= NBLK_PB;

    // ---- scatter path (atomic-bound; runs after BW paths drain) ----
    {
        const int range = bid & (NRANGE - 1);
        const int lo = range * RNODES, hi = lo + RNODES;
        const int stride = (NBLK_SC >> 2) * 256;
        for (int e = (bid >> 2) * 256 + threadIdx.x; e < EE; e += stride) {
            int d = ei[EE + e];
            if (d >= lo && d < hi) {
                int pos = atomicAdd(&cursor[d], 1);
                if (pos < CAP) csr[d * CAP + pos] = (unsigned short)ei[e];
            }
        }
    }
}

// ---------------- attention aggregation over fp8 rows: 8 edges per wave-iteration ----------
// half-wave h takes 4 consecutive edges; each half-wave covers a full 256-col row.
__global__ __launch_bounds__(256) void k_aggregate(const unsigned char* __restrict__ f8,
                                                   const float* __restrict__ e_src,
                                                   const int* __restrict__ cursor,
                                                   const unsigned short* __restrict__ csr,
                                                   unsigned short* __restrict__ agg) {
    int wave = threadIdx.x >> 6, lane = threadIdx.x & 63;
    int n = blockIdx.x * 4 + wave;
    if (n >= NN) return;
    int deg = cursor[n];
    if (deg > CAP) deg = CAP;
    const unsigned short* row = csr + (size_t)n * CAP;
    const int half = lane >> 5;
    const int col8 = (lane & 31) * 8;

    float acc[8] = {0.f, 0.f, 0.f, 0.f, 0.f, 0.f, 0.f, 0.f};
    float den = 0.f;

    int p = 0;
    #pragma unroll 2
    for (; p + 8 <= deg; p += 8) {
        int b = p + 4 * half;
        int s0 = row[b + 0];
        int s1 = row[b + 1];
        int s2 = row[b + 2];
        int s3 = row[b + 3];
        float w0 = e_src[s0], w1 = e_src[s1], w2 = e_src[s2], w3 = e_src[s3];
        uint2 r0 = *reinterpret_cast<const uint2*>(f8 + (size_t)s0 * DIM + col8);
        uint2 r1 = *reinterpret_cast<const uint2*>(f8 + (size_t)s1 * DIM + col8);
        uint2 r2 = *reinterpret_cast<const uint2*>(f8 + (size_t)s2 * DIM + col8);
        uint2 r3 = *reinterpret_cast<const uint2*>(f8 + (size_t)s3 * DIM + col8);
        fp8x8_fma(acc, r0, w0);
        fp8x8_fma(acc, r1, w1);
        fp8x8_fma(acc, r2, w2);
        fp8x8_fma(acc, r3, w3);
        den += (w0 + w1) + (w2 + w3);
    }
    for (; p < deg; p += 2) {
        int idx = p + half;
        bool valid = idx < deg;
        int s0 = row[valid ? idx : 0];
        float w0 = valid ? e_src[s0] : 0.f;
        uint2 r0 = *reinterpret_cast<const uint2*>(f8 + (size_t)s0 * DIM + col8);
        fp8x8_fma(acc, r0, w0);
        den += w0;
    }

    den += __shfl_xor(den, 32);
    float inv = (deg > 0 && den > 0.f) ? 1.f / den : 0.f;
    #pragma unroll
    for (int j = 0; j < 8; ++j) acc[j] += __shfl_xor(acc[j], 32);

    if (half == 0) {
        bf16x8 o;
        #pragma unroll
        for (int j = 0; j < 8; ++j) o[j] = (short)f2bf(acc[j] * inv);
        *reinterpret_cast<bf16x8*>(agg + (size_t)n * DIM + col8) = o;
    }
}

// ---------------- fused MFMA GEMM + LN + ReLU + score + packs (+ colsum on last layer) -----
#define LDS_STRIDE 264
__global__ __launch_bounds__(256) void k_gemm_ln(const unsigned short* __restrict__ hin,
                                                 const unsigned short* __restrict__ agg,
                                                 const unsigned short* __restrict__ Bp,
                                                 const float* __restrict__ bias,
                                                 const float* __restrict__ gamma_l,
                                                 const float* __restrict__ beta_l,
                                                 const float* __restrict__ w_src_next,  // null on last layer
                                                 unsigned short* __restrict__ hout,
                                                 unsigned char* __restrict__ f8out,     // null on last layer
                                                 float* __restrict__ e_src,
                                                 float* __restrict__ colsum) {          // non-null on last layer
    __shared__ __align__(16) unsigned char lds_raw[4 * 16 * LDS_STRIDE * 2];  // 33792 B
    unsigned short* bbuf0 = (unsigned short*)lds_raw;           // 16 KB
    unsigned short* bbuf1 = bbuf0 + 8192;                       // 16 KB
    int w = threadIdx.x >> 6, lane = threadIdx.x & 63;
    int c = lane & 15, q = lane >> 4;
    int m0 = blockIdx.x * 64 + w * 16;

    auto stage = [&](int ks, unsigned short* buf) {
        const unsigned short* g = Bp + (size_t)ks * 8192 + w * 2048 + lane * 8;
        unsigned short* l = buf + w * 2048;   // wave-uniform base
        #pragma unroll
        for (int i = 0; i < 4; ++i)
            gload_lds16(g + i * 512, l + i * 512);
    };

    f32x4 acc[16];
    #pragma unroll
    for (int nf = 0; nf < 16; ++nf) {
        float b = bias[nf * 16 + c];
        acc[nf] = (f32x4){b, b, b, b};
    }

    stage(0, bbuf0);
    bf16x8 a_cur = *reinterpret_cast<const bf16x8*>(hin + (size_t)(m0 + c) * DIM + q * 8);
    __syncthreads();

    #pragma unroll
    for (int ks = 0; ks < 16; ++ks) {
        const unsigned short* bb = (ks & 1) ? bbuf1 : bbuf0;
        unsigned short* bnext    = (ks & 1) ? bbuf0 : bbuf1;
        bf16x8 a_next = a_cur;
        if (ks + 1 < 16) {
            stage(ks + 1, bnext);
            const int kk1 = (ks + 1) * 32;
            const unsigned short* hs = (kk1 < DIM) ? hin : agg;
            a_next = *reinterpret_cast<const bf16x8*>(
                hs + (size_t)(m0 + c) * DIM + (kk1 & (DIM - 1)) + q * 8);
        }
        #pragma unroll
        for (int nf = 0; nf < 16; ++nf) {
            bf16x8 bfr = *reinterpret_cast<const bf16x8*>(bb + nf * 512 + lane * 8);
            acc[nf] = __builtin_amdgcn_mfma_f32_16x16x32_bf16(a_cur, bfr, acc[nf], 0, 0, 0);
        }
        __syncthreads();
        a_cur = a_next;
    }

    // LN + ReLU + next-layer score
    #pragma unroll
    for (int r = 0; r < 4; ++r) {
        float s = 0.f, s2 = 0.f;
        #pragma unroll
        for (int nf = 0; nf < 16; ++nf) {
            float v = acc[nf][r];
            s += v; s2 += v * v;
        }
        #pragma unroll
        for (int msk = 1; msk < 16; msk <<= 1) {
            s  += __shfl_xor(s, msk);
            s2 += __shfl_xor(s2, msk);
        }
        float mu = s * (1.f / DIM);
        float var = s2 * (1.f / DIM) - mu * mu;
        float rstd = rsqrtf(var + 1e-5f);
        float sc = 0.f;
        #pragma unroll
        for (int nf = 0; nf < 16; ++nf) {
            float v = fmaxf(gamma_l[nf * 16 + c] * (acc[nf][r] - mu) * rstd + beta_l[nf * 16 + c], 0.f);
            acc[nf][r] = v;
            if (w_src_next) sc += v * w_src_next[nf * 16 + c];
        }
        if (w_src_next) {
            #pragma unroll
            for (int msk = 1; msk < 16; msk <<= 1) sc += __shfl_xor(sc, msk);
            int row = m0 + q * 4 + r;
            if (c == 0 && row < NN) e_src[row] = __expf(sc);
        }
    }

    // pack 16 rows via per-wave LDS staging (aliases B buffers; loop fully barriered)
    unsigned short* myl = (unsigned short*)lds_raw + w * 16 * LDS_STRIDE;
    #pragma unroll
    for (int nf = 0; nf < 16; ++nf) {
        #pragma unroll
        for (int r = 0; r < 4; ++r)
            myl[(q * 4 + r) * LDS_STRIDE + nf * 16 + c] = f2bf(acc[nf][r]);
    }
    #pragma unroll
    for (int i = 0; i < 8; ++i) {
        int row16 = 2 * i + (lane >> 5);
        bf16x8 v = *reinterpret_cast<const bf16x8*>(myl + row16 * LDS_STRIDE + (lane & 31) * 8);
        int grow = m0 + row16;
        if (grow < NN) {
            *reinterpret_cast<bf16x8*>(hout + (size_t)grow * DIM + (lane & 31) * 8) = v;
            if (f8out) {
                uint2 pk;
                pk.x = fp8x4_enc(bf2f((unsigned short)v[0]), bf2f((unsigned short)v[1]),
                                 bf2f((unsigned short)v[2]), bf2f((unsigned short)v[3]));
                pk.y = fp8x4_enc(bf2f((unsigned short)v[4]), bf2f((unsigned short)v[5]),
                                 bf2f((unsigned short)v[6]), bf2f((unsigned short)v[7]));
                *reinterpret_cast<uint2*>(f8out + (size_t)grow * DIM + (lane & 31) * 8) = pk;
            }
        }
    }

    // fused column-sum of this block's 64 output rows (last layer only; rows sit in LDS)
    if (colsum) {
        __syncthreads();
        int t = threadIdx.x;
        float s = 0.f;
        unsigned short* l0 = (unsigned short*)lds_raw;
        #pragma unroll 4
        for (int r = 0; r < 64; ++r) {
            if (blockIdx.x * 64 + r < NN)
                s += bf2f(l0[((r >> 4) * 16 + (r & 15)) * LDS_STRIDE + t]);
        }
        atomicAdd(&colsum[t], s);
    }
}

// ---------------- final: out = mean(h) + mean(x) @ W_skip + b_skip ----------------
__global__ __launch_bounds__(256) void k_final(const float* __restrict__ hsum, const float* __restrict__ xsum,
                                               const float* __restrict__ W_skip, const float* __restrict__ b_skip,
                                               float* __restrict__ out) {
    int j = threadIdx.x;
    float acc = 0.f;
    const float invN = 1.f / (float)NN;
    for (int i = 0; i < DIM; ++i) acc += (xsum[i] * invN) * W_skip[(size_t)i * DIM + j];
    out[j] = hsum[j] * invN + acc + b_skip[j];
}

extern "C" void kernel_launch(void* const* d_in, const int* in_sizes, int n_in,
                              void* d_out, int out_size, void* d_ws, size_t ws_size,
                              hipStream_t stream) {
    const float* x      = (const float*)d_in[0];
    const int*   ei     = (const int*)d_in[1];
    const float* W_sage = (const float*)d_in[2];
    const float* b_sage = (const float*)d_in[3];
    const float* gamma  = (const float*)d_in[4];
    const float* beta   = (const float*)d_in[5];
    const float* W_attn = (const float*)d_in[6];
    // d_in[7] = b_attn: cancels in the per-dst softmax — unused.
    const float* W_skip = (const float*)d_in[8];
    const float* b_skip = (const float*)d_in[9];
    float* out = (float*)d_out;

    // ---- workspace layout ----
    const size_t ND = (size_t)NN * DIM;
    unsigned short* hx   = (unsigned short*)d_ws;        // ND bf16
    unsigned short* hA   = hx + ND;                      // ND bf16
    unsigned short* hB   = hA + ND;                      // ND bf16
    unsigned short* agg  = hB + ND;                      // ND bf16
    unsigned short* Bp3  = agg + ND;                     // 3*512*256 bf16 (all layers packed)
    unsigned char*  f8a  = (unsigned char*)(Bp3 + 3 * (size_t)KDIM * DIM + 64);  // ND fp8
    unsigned char*  f8b  = f8a + ND;                     // ND fp8
    float* e_src  = (float*)(f8b + ND + 64);             // NN (pad for OOB A-read slack)
    float* colsum = e_src + NN;                          // DIM
    float* xsum   = colsum + DIM;                        // DIM
    int*   cursor = (int*)(xsum + DIM);                  // NN degree counters
    unsigned short* csr = (unsigned short*)(cursor + NN);  // NN*CAP ushorts (8 MB)

    hipError_t err;
    err = hipMemsetAsync(cursor, 0, (size_t)NN * sizeof(int), stream); (void)err;
    err = hipMemsetAsync(colsum, 0, 2 * DIM * sizeof(float), stream); (void)err;

    // merged setup: prep | xsum | packB3 | scatter (independent; BW paths lead)
    k_setup<<<NBLK_SETUP, 256, 0, stream>>>(ei, cursor, csr,
                                            x, W_attn + DIM, hx, f8a, e_src, xsum,
                                            W_sage, Bp3);

    unsigned short* hbufs[4]  = {hx, hA, hB, hA};
    unsigned char*  f8bufs[3] = {f8a, f8b, f8a};   // ping-pong; layer-2 f8 output unused
    for (int l = 0; l < NLAYER; ++l) {
        const bool last = (l == NLAYER - 1);
        k_aggregate<<<(NN + 3) / 4, 256, 0, stream>>>(f8bufs[l], e_src, cursor, csr, agg);
        const float* wnext = last ? nullptr : (W_attn + (size_t)(l + 1) * KDIM + DIM);
        unsigned char* f8next = last ? nullptr : f8bufs[l + 1];
        k_gemm_ln<<<(NN + 63) / 64, 256, 0, stream>>>(
            hbufs[l], agg, Bp3 + (size_t)l * KDIM * DIM, b_sage + (size_t)l * DIM,
            gamma + (size_t)l * DIM, beta + (size_t)l * DIM,
            wnext, hbufs[l + 1], f8next, e_src,
            last ? colsum : nullptr);
    }

    k_final<<<1, 256, 0, stream>>>(colsum, xsum, W_skip, b_skip, out);
}

// Round 21
// 449.864 us; speedup vs baseline: 1.2501x; 1.0095x over previous
//
#include <hip/hip_runtime.h>
#include <hip/hip_bf16.h>

#define NN 50000
#define EE 1600000
#define DIM 256
#define KDIM 512
#define NLAYER 3
#define NRANGE 4
#define RNODES (NN / NRANGE)   // 12500
#define CAP 80                 // fixed CSR row capacity; P(deg>80) ~ 1e-17 per node

// setup-kernel grid partition: BW-bound paths first, atomic-bound scatter last
#define NBLK_PREP ((NN + 3) / 4)           // 12500
#define NBLK_CS   1024
#define NBLK_PB   (3 * KDIM * DIM / 256)   // 1536
#define NBLK_SC   (NRANGE * 1568)          // 6272 scatter blocks
#define NBLK_SETUP (NBLK_PREP + NBLK_CS + NBLK_PB + NBLK_SC)

using bf16x8 = __attribute__((ext_vector_type(8))) short;
using f32x4  = __attribute__((ext_vector_type(4))) float;
using f32x2  = __attribute__((ext_vector_type(2))) float;

static __device__ __forceinline__ unsigned short f2bf(float f) {
    unsigned u = __builtin_bit_cast(unsigned, f);
    unsigned r = (u + 0x7FFFu + ((u >> 16) & 1u)) >> 16;   // RNE
    return (unsigned short)r;
}
static __device__ __forceinline__ float bf2f(unsigned short s) {
    return __builtin_bit_cast(float, (unsigned)s << 16);
}

// ---- async global->LDS, 16B per lane. LDS dest is wave-uniform base + lane*16 (G21).
static __device__ __forceinline__ void gload_lds16(const void* g, void* l) {
    __builtin_amdgcn_global_load_lds(
        reinterpret_cast<const __attribute__((address_space(1))) void*>(
            reinterpret_cast<uintptr_t>(g)),
        reinterpret_cast<__attribute__((address_space(3))) void*>(
            static_cast<unsigned>(reinterpret_cast<uintptr_t>(l))),
        16, 0, 0);
}

// ---- fp8 e4m3 (OCP) helpers ----
#if defined(__has_builtin) && __has_builtin(__builtin_amdgcn_cvt_pk_f32_fp8) && __has_builtin(__builtin_amdgcn_cvt_pk_fp8_f32)
#define FP8_NATIVE 1
#else
#define FP8_NATIVE 0
#endif

template <bool HI>
static __device__ __forceinline__ f32x2 fp8x2_dec(unsigned w) {
#if FP8_NATIVE
    return __builtin_amdgcn_cvt_pk_f32_fp8((int)w, HI);
#else
    unsigned v = HI ? (w >> 16) : w;
    unsigned b0 = v & 0xFFu, b1 = (v >> 8) & 0xFFu;
    unsigned u0 = ((b0 & 0x80u) << 24) | ((b0 & 0x7Fu) << 20);
    unsigned u1 = ((b1 & 0x80u) << 24) | ((b1 & 0x7Fu) << 20);
    f32x2 r;
    r[0] = __builtin_bit_cast(float, u0) * 0x1p120f;
    r[1] = __builtin_bit_cast(float, u1) * 0x1p120f;
    return r;
#endif
}

#if !FP8_NATIVE
static __device__ __forceinline__ unsigned fp8_enc1(float f) {
    unsigned u = __builtin_bit_cast(unsigned, f * 0x1p-120f);
    unsigned s = (u >> 24) & 0x80u;
    unsigned m = u & 0x7FFFFFFFu;
    m = m + 0x7FFFFu + ((m >> 20) & 1u);
    return s | ((m >> 20) & 0x7Fu);
}
#endif

static __device__ __forceinline__ unsigned fp8x4_enc(float a, float b, float c, float d) {
#if FP8_NATIVE
    int w = __builtin_amdgcn_cvt_pk_fp8_f32(a, b, 0, false);
    w = __builtin_amdgcn_cvt_pk_fp8_f32(c, d, w, true);
    return (unsigned)w;
#else
    return fp8_enc1(a) | (fp8_enc1(b) << 8) | (fp8_enc1(c) << 16) | (fp8_enc1(d) << 24);
#endif
}

// decode 8 fp8 (uint2) scaled by wg into acc[0..7]
static __device__ __forceinline__ void fp8x8_fma(float* acc, uint2 r, float wg) {
    f32x2 p0 = fp8x2_dec<false>(r.x);
    f32x2 p1 = fp8x2_dec<true>(r.x);
    f32x2 p2 = fp8x2_dec<false>(r.y);
    f32x2 p3 = fp8x2_dec<true>(r.y);
    acc[0] += wg * p0[0]; acc[1] += wg * p0[1];
    acc[2] += wg * p1[0]; acc[3] += wg * p1[1];
    acc[4] += wg * p2[0]; acc[5] += wg * p2[1];
    acc[6] += wg * p3[0]; acc[7] += wg * p3[1];
}

// ---------------- MERGED setup: prep | xsum | packB3 | scatter (independent block ranges) ---
// BW-bound paths first (finish in ~25 us at full width); atomic-bound scatter backfills and
// then runs nearly uncontended.
__global__ __launch_bounds__(256) void k_setup(const int* __restrict__ ei,
                                               int* __restrict__ cursor,
                                               unsigned short* __restrict__ csr,
                                               const float* __restrict__ x,
                                               const float* __restrict__ w_src0,
                                               unsigned short* __restrict__ hout,
                                               unsigned char* __restrict__ f8out,
                                               float* __restrict__ e_src,
                                               float* __restrict__ xsum,
                                               const float* __restrict__ W_all,
                                               unsigned short* __restrict__ Bp3) {
    int bid = blockIdx.x;

    if (bid < NBLK_PREP) {
        // ---- prep path: x -> bf16 + fp8 + layer-0 scores ----
        int wave = threadIdx.x >> 6, lane = threadIdx.x & 63;
        int n = bid * 4 + wave;
        if (n >= NN) return;
        const float4 v = *reinterpret_cast<const float4*>(x + (size_t)n * DIM + lane * 4);
        const float4 wv = *reinterpret_cast<const float4*>(w_src0 + lane * 4);
        float sc = v.x * wv.x + v.y * wv.y + v.z * wv.z + v.w * wv.w;
        #pragma unroll
        for (int m = 32; m; m >>= 1) sc += __shfl_xor(sc, m);
        if (lane == 0) e_src[n] = __expf(sc);
        ushort4 o;
        o.x = f2bf(v.x); o.y = f2bf(v.y); o.z = f2bf(v.z); o.w = f2bf(v.w);
        *reinterpret_cast<ushort4*>(hout + (size_t)n * DIM + lane * 4) = o;
        *reinterpret_cast<unsigned*>(f8out + (size_t)n * DIM + lane * 4) =
            fp8x4_enc(v.x, v.y, v.z, v.w);
        return;
    }
    bid -= NBLK_PREP;

    if (bid < NBLK_CS) {
        // ---- xsum path (column sums of x) ----
        int j = threadIdx.x;
        float s = 0.f;
        for (int r = bid; r < NN; r += NBLK_CS) s += x[(size_t)r * DIM + j];
        atomicAdd(&xsum[j], s);
        return;
    }
    bid -= NBLK_CS;

    if (bid < NBLK_PB) {
        // ---- packB3 path: all 3 layers' W -> lane-linear MFMA-B fragments ----
        int gid = bid * 256 + threadIdx.x;
        int l   = gid >> 17;                 // 131072 elements per layer
        int tid = gid & 131071;
        int j    = tid & 7;
        int lane = (tid >> 3) & 63;
        int nf   = (tid >> 9) & 15;
        int ks   = tid >> 13;
        int c = lane & 15, q = lane >> 4;
        Bp3[gid] = f2bf(W_all[(size_t)l * KDIM * DIM + (size_t)(ks * 32 + q * 8 + j) * DIM + nf * 16 + c]);
        return;
    }
    bid -= NBLK_PB;

    // ---- scatter path (atomic-bound; runs after BW paths drain) ----
    {
        const int range = bid & (NRANGE - 1);
        const int lo = range * RNODES, hi = lo + RNODES;
        const int stride = (NBLK_SC >> 2) * 256;
        for (int e = (bid >> 2) * 256 + threadIdx.x; e < EE; e += stride) {
            int d = ei[EE + e];
            if (d >= lo && d < hi) {
                int pos = atomicAdd(&cursor[d], 1);
                if (pos < CAP) csr[d * CAP + pos] = (unsigned short)ei[e];
            }
        }
    }
}

// ---------------- attention aggregation over fp8 rows: 8 edges per wave-iteration ----------
// half-wave h takes 4 consecutive edges; each half-wave covers a full 256-col row.
__global__ __launch_bounds__(256) void k_aggregate(const unsigned char* __restrict__ f8,
                                                   const float* __restrict__ e_src,
                                                   const int* __restrict__ cursor,
                                                   const unsigned short* __restrict__ csr,
                                                   unsigned short* __restrict__ agg) {
    int wave = threadIdx.x >> 6, lane = threadIdx.x & 63;
    int n = blockIdx.x * 4 + wave;
    if (n >= NN) return;
    int deg = cursor[n];
    if (deg > CAP) deg = CAP;
    const unsigned short* row = csr + (size_t)n * CAP;
    const int half = lane >> 5;
    const int col8 = (lane & 31) * 8;

    float acc[8] = {0.f, 0.f, 0.f, 0.f, 0.f, 0.f, 0.f, 0.f};
    float den = 0.f;

    int p = 0;
    #pragma unroll 2
    for (; p + 8 <= deg; p += 8) {
        int b = p + 4 * half;
        int s0 = row[b + 0];
        int s1 = row[b + 1];
        int s2 = row[b + 2];
        int s3 = row[b + 3];
        float w0 = e_src[s0], w1 = e_src[s1], w2 = e_src[s2], w3 = e_src[s3];
        uint2 r0 = *reinterpret_cast<const uint2*>(f8 + (size_t)s0 * DIM + col8);
        uint2 r1 = *reinterpret_cast<const uint2*>(f8 + (size_t)s1 * DIM + col8);
        uint2 r2 = *reinterpret_cast<const uint2*>(f8 + (size_t)s2 * DIM + col8);
        uint2 r3 = *reinterpret_cast<const uint2*>(f8 + (size_t)s3 * DIM + col8);
        fp8x8_fma(acc, r0, w0);
        fp8x8_fma(acc, r1, w1);
        fp8x8_fma(acc, r2, w2);
        fp8x8_fma(acc, r3, w3);
        den += (w0 + w1) + (w2 + w3);
    }
    for (; p < deg; p += 2) {
        int idx = p + half;
        bool valid = idx < deg;
        int s0 = row[valid ? idx : 0];
        float w0 = valid ? e_src[s0] : 0.f;
        uint2 r0 = *reinterpret_cast<const uint2*>(f8 + (size_t)s0 * DIM + col8);
        fp8x8_fma(acc, r0, w0);
        den += w0;
    }

    den += __shfl_xor(den, 32);
    float inv = (deg > 0 && den > 0.f) ? 1.f / den : 0.f;
    #pragma unroll
    for (int j = 0; j < 8; ++j) acc[j] += __shfl_xor(acc[j], 32);

    if (half == 0) {
        bf16x8 o;
        #pragma unroll
        for (int j = 0; j < 8; ++j) o[j] = (short)f2bf(acc[j] * inv);
        *reinterpret_cast<bf16x8*>(agg + (size_t)n * DIM + col8) = o;
    }
}

// ---------------- fused MFMA GEMM + LN + ReLU + score + packs (+ colsum on last layer) -----
#define LDS_STRIDE 264
__global__ __launch_bounds__(256) void k_gemm_ln(const unsigned short* __restrict__ hin,
                                                 const unsigned short* __restrict__ agg,
                                                 const unsigned short* __restrict__ Bp,
                                                 const float* __restrict__ bias,
                                                 const float* __restrict__ gamma_l,
                                                 const float* __restrict__ beta_l,
                                                 const float* __restrict__ w_src_next,  // null on last layer
                                                 unsigned short* __restrict__ hout,
                                                 unsigned char* __restrict__ f8out,     // null on last layer
                                                 float* __restrict__ e_src,
                                                 float* __restrict__ colsum) {          // non-null on last layer
    __shared__ __align__(16) unsigned char lds_raw[4 * 16 * LDS_STRIDE * 2];  // 33792 B
    unsigned short* bbuf0 = (unsigned short*)lds_raw;           // 16 KB
    unsigned short* bbuf1 = bbuf0 + 8192;                       // 16 KB
    int w = threadIdx.x >> 6, lane = threadIdx.x & 63;
    int c = lane & 15, q = lane >> 4;
    int m0 = blockIdx.x * 64 + w * 16;

    auto stage = [&](int ks, unsigned short* buf) {
        const unsigned short* g = Bp + (size_t)ks * 8192 + w * 2048 + lane * 8;
        unsigned short* l = buf + w * 2048;   // wave-uniform base
        #pragma unroll
        for (int i = 0; i < 4; ++i)
            gload_lds16(g + i * 512, l + i * 512);
    };

    f32x4 acc[16];
    #pragma unroll
    for (int nf = 0; nf < 16; ++nf) {
        float b = bias[nf * 16 + c];
        acc[nf] = (f32x4){b, b, b, b};
    }

    stage(0, bbuf0);
    bf16x8 a_cur = *reinterpret_cast<const bf16x8*>(hin + (size_t)(m0 + c) * DIM + q * 8);
    __syncthreads();

    #pragma unroll
    for (int ks = 0; ks < 16; ++ks) {
        const unsigned short* bb = (ks & 1) ? bbuf1 : bbuf0;
        unsigned short* bnext    = (ks & 1) ? bbuf0 : bbuf1;
        bf16x8 a_next = a_cur;
        if (ks + 1 < 16) {
            stage(ks + 1, bnext);
            const int kk1 = (ks + 1) * 32;
            const unsigned short* hs = (kk1 < DIM) ? hin : agg;
            a_next = *reinterpret_cast<const bf16x8*>(
                hs + (size_t)(m0 + c) * DIM + (kk1 & (DIM - 1)) + q * 8);
        }
        #pragma unroll
        for (int nf = 0; nf < 16; ++nf) {
            bf16x8 bfr = *reinterpret_cast<const bf16x8*>(bb + nf * 512 + lane * 8);
            acc[nf] = __builtin_amdgcn_mfma_f32_16x16x32_bf16(a_cur, bfr, acc[nf], 0, 0, 0);
        }
        __syncthreads();
        a_cur = a_next;
    }

    // LN + ReLU + next-layer score
    #pragma unroll
    for (int r = 0; r < 4; ++r) {
        float s = 0.f, s2 = 0.f;
        #pragma unroll
        for (int nf = 0; nf < 16; ++nf) {
            float v = acc[nf][r];
            s += v; s2 += v * v;
        }
        #pragma unroll
        for (int msk = 1; msk < 16; msk <<= 1) {
            s  += __shfl_xor(s, msk);
            s2 += __shfl_xor(s2, msk);
        }
        float mu = s * (1.f / DIM);
        float var = s2 * (1.f / DIM) - mu * mu;
        float rstd = rsqrtf(var + 1e-5f);
        float sc = 0.f;
        #pragma unroll
        for (int nf = 0; nf < 16; ++nf) {
            float v = fmaxf(gamma_l[nf * 16 + c] * (acc[nf][r] - mu) * rstd + beta_l[nf * 16 + c], 0.f);
            acc[nf][r] = v;
            if (w_src_next) sc += v * w_src_next[nf * 16 + c];
        }
        if (w_src_next) {
            #pragma unroll
            for (int msk = 1; msk < 16; msk <<= 1) sc += __shfl_xor(sc, msk);
            int row = m0 + q * 4 + r;
            if (c == 0 && row < NN) e_src[row] = __expf(sc);
        }
    }

    // pack 16 rows via per-wave LDS staging (aliases B buffers; loop fully barriered)
    unsigned short* myl = (unsigned short*)lds_raw + w * 16 * LDS_STRIDE;
    #pragma unroll
    for (int nf = 0; nf < 16; ++nf) {
        #pragma unroll
        for (int r = 0; r < 4; ++r)
            myl[(q * 4 + r) * LDS_STRIDE + nf * 16 + c] = f2bf(acc[nf][r]);
    }
    #pragma unroll
    for (int i = 0; i < 8; ++i) {
        int row16 = 2 * i + (lane >> 5);
        bf16x8 v = *reinterpret_cast<const bf16x8*>(myl + row16 * LDS_STRIDE + (lane & 31) * 8);
        int grow = m0 + row16;
        if (grow < NN) {
            *reinterpret_cast<bf16x8*>(hout + (size_t)grow * DIM + (lane & 31) * 8) = v;
            if (f8out) {
                uint2 pk;
                pk.x = fp8x4_enc(bf2f((unsigned short)v[0]), bf2f((unsigned short)v[1]),
                                 bf2f((unsigned short)v[2]), bf2f((unsigned short)v[3]));
                pk.y = fp8x4_enc(bf2f((unsigned short)v[4]), bf2f((unsigned short)v[5]),
                                 bf2f((unsigned short)v[6]), bf2f((unsigned short)v[7]));
                *reinterpret_cast<uint2*>(f8out + (size_t)grow * DIM + (lane & 31) * 8) = pk;
            }
        }
    }

    // fused column-sum of this block's 64 output rows (last layer only; rows sit in LDS)
    if (colsum) {
        __syncthreads();
        int t = threadIdx.x;
        float s = 0.f;
        unsigned short* l0 = (unsigned short*)lds_raw;
        #pragma unroll 4
        for (int r = 0; r < 64; ++r) {
            if (blockIdx.x * 64 + r < NN)
                s += bf2f(l0[((r >> 4) * 16 + (r & 15)) * LDS_STRIDE + t]);
        }
        atomicAdd(&colsum[t], s);
    }
}

// ---------------- final: out = mean(h) + mean(x) @ W_skip + b_skip (4-way split-K) --------
__global__ __launch_bounds__(1024) void k_final(const float* __restrict__ hsum,
                                                const float* __restrict__ xsum,
                                                const float* __restrict__ W_skip,
                                                const float* __restrict__ b_skip,
                                                float* __restrict__ out) {
    __shared__ float part[4][DIM];
    int j = threadIdx.x & (DIM - 1);
    int g = threadIdx.x >> 8;          // 0..3, each handles 64 i-values
    const float invN = 1.f / (float)NN;
    float acc = 0.f;
    for (int i = g * 64; i < g * 64 + 64; ++i)
        acc += (xsum[i] * invN) * W_skip[(size_t)i * DIM + j];
    part[g][j] = acc;
    __syncthreads();
    if (g == 0)
        out[j] = hsum[j] * invN + b_skip[j]
               + ((part[0][j] + part[1][j]) + (part[2][j] + part[3][j]));
}

extern "C" void kernel_launch(void* const* d_in, const int* in_sizes, int n_in,
                              void* d_out, int out_size, void* d_ws, size_t ws_size,
                              hipStream_t stream) {
    const float* x      = (const float*)d_in[0];
    const int*   ei     = (const int*)d_in[1];
    const float* W_sage = (const float*)d_in[2];
    const float* b_sage = (const float*)d_in[3];
    const float* gamma  = (const float*)d_in[4];
    const float* beta   = (const float*)d_in[5];
    const float* W_attn = (const float*)d_in[6];
    // d_in[7] = b_attn: cancels in the per-dst softmax — unused.
    const float* W_skip = (const float*)d_in[8];
    const float* b_skip = (const float*)d_in[9];
    float* out = (float*)d_out;

    // ---- workspace layout (cursor|colsum|xsum contiguous -> single memset) ----
    const size_t ND = (size_t)NN * DIM;
    unsigned short* hx   = (unsigned short*)d_ws;        // ND bf16
    unsigned short* hA   = hx + ND;                      // ND bf16
    unsigned short* hB   = hA + ND;                      // ND bf16
    unsigned short* agg  = hB + ND;                      // ND bf16
    unsigned short* Bp3  = agg + ND;                     // 3*512*256 bf16 (all layers packed)
    unsigned char*  f8a  = (unsigned char*)(Bp3 + 3 * (size_t)KDIM * DIM + 64);  // ND fp8
    unsigned char*  f8b  = f8a + ND;                     // ND fp8
    float* e_src  = (float*)(f8b + ND + 64);             // NN (pad for OOB A-read slack)
    int*   cursor = (int*)(e_src + NN);                  // NN degree counters
    float* colsum = (float*)(cursor + NN);               // DIM
    float* xsum   = colsum + DIM;                        // DIM
    unsigned short* csr = (unsigned short*)(xsum + DIM); // NN*CAP ushorts (8 MB)

    hipError_t err;
    err = hipMemsetAsync(cursor, 0, (size_t)(NN + 2 * DIM) * sizeof(int), stream); (void)err;

    // merged setup: prep | xsum | packB3 | scatter (independent; BW paths lead)
    k_setup<<<NBLK_SETUP, 256, 0, stream>>>(ei, cursor, csr,
                                            x, W_attn + DIM, hx, f8a, e_src, xsum,
                                            W_sage, Bp3);

    unsigned short* hbufs[4]  = {hx, hA, hB, hA};
    unsigned char*  f8bufs[3] = {f8a, f8b, f8a};   // ping-pong; layer-2 f8 output unused
    for (int l = 0; l < NLAYER; ++l) {
        const bool last = (l == NLAYER - 1);
        k_aggregate<<<(NN + 3) / 4, 256, 0, stream>>>(f8bufs[l], e_src, cursor, csr, agg);
        const float* wnext = last ? nullptr : (W_attn + (size_t)(l + 1) * KDIM + DIM);
        unsigned char* f8next = last ? nullptr : f8bufs[l + 1];
        k_gemm_ln<<<(NN + 63) / 64, 256, 0, stream>>>(
            hbufs[l], agg, Bp3 + (size_t)l * KDIM * DIM, b_sage + (size_t)l * DIM,
            gamma + (size_t)l * DIM, beta + (size_t)l * DIM,
            wnext, hbufs[l + 1], f8next, e_src,
            last ? colsum : nullptr);
    }

    k_final<<<1, 1024, 0, stream>>>(colsum, xsum, W_skip, b_skip, out);
}